// Round 11
// baseline (366.243 us; speedup 1.0000x reference)
//
#include <hip/hip_runtime.h>

#define DD 256
#define NGRAPH 64
#define NCLS 60
#define BN_EPS 1e-5f
#define SCAN_B 256
#define AGG_BLOCKS 2048
#define AGG_WAVES (AGG_BLOCKS * 4)
#define POOL_PARTS 16

typedef __attribute__((ext_vector_type(8))) short bf16x8;
typedef __attribute__((ext_vector_type(8))) unsigned short u16x8;
typedef __attribute__((ext_vector_type(4))) float f32x4;

__device__ __forceinline__ unsigned short f2bf(float f) {
    union { float f; unsigned u; } v;
    v.f = f;
    unsigned r = v.u + 0x7FFFu + ((v.u >> 16) & 1u);  // RNE
    return (unsigned short)(r >> 16);
}
__device__ __forceinline__ float bf2f(unsigned short u) {
    union { unsigned u; float f; } v;
    v.u = ((unsigned)u) << 16;
    return v.f;
}

// ---------------- degree ----------------
__global__ void k_degcount(const int* __restrict__ dst, int E, int* __restrict__ degcnt) {
    int e = blockIdx.x * blockDim.x + threadIdx.x;
    if (e < E) atomicAdd(&degcnt[dst[e]], 1);
}

// ---------------- scan phase 1 (blocks 0..nblk-1) + W transpose (blocks nblk..nblk+255) ----------------
__global__ __launch_bounds__(256) void k_scan1wt(const int* __restrict__ in, int n, int nblk,
                                                 int* __restrict__ out, int* __restrict__ bsum,
                                                 const float* __restrict__ W,
                                                 unsigned short* __restrict__ Wt) {
    if (blockIdx.x >= nblk) {
        int col = blockIdx.x - nblk;          // 0..255: column of W -> row of Wt
        int k = threadIdx.x;
        Wt[col * DD + k] = f2bf(W[k * DD + col]);
        return;
    }
    __shared__ int sm[SCAN_B];
    int i = blockIdx.x * SCAN_B + threadIdx.x;
    int v = (i < n) ? in[i] : 0;
    sm[threadIdx.x] = v;
    __syncthreads();
    int acc = v;
    for (int off = 1; off < SCAN_B; off <<= 1) {
        int t = (threadIdx.x >= off) ? sm[threadIdx.x - off] : 0;
        __syncthreads();
        acc += t;
        sm[threadIdx.x] = acc;
        __syncthreads();
    }
    if (i < n) out[i] = acc - v;
    if (threadIdx.x == SCAN_B - 1) bsum[blockIdx.x] = acc;
}

__global__ void k_scan2(int* __restrict__ bsum, int nb, int* __restrict__ total) {
    __shared__ int sm[SCAN_B];
    __shared__ int carry;
    if (threadIdx.x == 0) carry = 0;
    __syncthreads();
    for (int base = 0; base < nb; base += SCAN_B) {
        int i = base + threadIdx.x;
        int v = (i < nb) ? bsum[i] : 0;
        sm[threadIdx.x] = v;
        __syncthreads();
        int acc = v;
        for (int off = 1; off < SCAN_B; off <<= 1) {
            int t = (threadIdx.x >= off) ? sm[threadIdx.x - off] : 0;
            __syncthreads();
            acc += t;
            sm[threadIdx.x] = acc;
            __syncthreads();
        }
        if (i < nb) bsum[i] = carry + acc - v;
        __syncthreads();
        if (threadIdx.x == SCAN_B - 1) carry += acc;
        __syncthreads();
    }
    if (threadIdx.x == 0 && total) *total = carry;
}

// scan phase 3: finalize rowptr and initialize fill cursors
__global__ void k_scan3f(int* __restrict__ rowptr, int n, const int* __restrict__ bsum,
                         int* __restrict__ fillcur) {
    int i = blockIdx.x * SCAN_B + threadIdx.x;
    if (i < n) {
        int v = rowptr[i] + bsum[blockIdx.x];
        rowptr[i] = v;
        fillcur[i] = v;
    }
}

// ---------------- CSR bucket fill: packed 4B (src:16 | norm_bf16:16) ----------------
__global__ void k_fill(const int* __restrict__ src, const int* __restrict__ dst,
                       const int* __restrict__ degcnt, int* __restrict__ fillcur,
                       int E, unsigned* __restrict__ esw) {
    int e = blockIdx.x * blockDim.x + threadIdx.x;
    if (e >= E) return;
    int s = src[e], d = dst[e];
    float w = rsqrtf((float)(degcnt[s] + 1)) * rsqrtf((float)(degcnt[d] + 1));
    int slot = atomicAdd(&fillcur[d], 1);
    esw[slot] = (unsigned)s | ((unsigned)f2bf(w) << 16);  // N < 65536
}

// ---------------- persistent MFMA GEMM: Wt staged once, register-direct A, no K-loop barriers ----------------
#define GBM 128
__global__ __launch_bounds__(512) void k_gemm_mfma(const float* __restrict__ A,
                                                   const unsigned short* __restrict__ Wtg,
                                                   unsigned short* __restrict__ C, int M,
                                                   int ntiles) {
    __shared__ short Wt[DD * 256];  // full weight [n][k] bf16, XOR-swizzled, 128 KB
    const int tid = threadIdx.x;
    const int wave = tid >> 6;
    const int lane = tid & 63;
    const int frow = wave * 16 + (lane & 15);   // 0..127
    const int g = lane >> 4;                    // 0..3 -> k-subblock g*8

#pragma unroll
    for (int i = 0; i < 16; ++i) {
        int cid = tid + i * 512;
        int n = cid >> 5;
        int k0 = (cid & 31) * 8;
        bf16x8 pk = *(const bf16x8*)&Wtg[(size_t)n * DD + k0];
        int byte = (n * 512 + k0 * 2) ^ ((n & 7) << 4);
        *(bf16x8*)((char*)Wt + byte) = pk;
    }
    __syncthreads();

    for (int t = blockIdx.x; t < ntiles; t += gridDim.x) {
        const int row0 = t * GBM;
        const int grow = row0 + frow;
        const float* ap = (grow < M) ? &A[(size_t)grow * DD + g * 8] : nullptr;

        f32x4 acc[16];
#pragma unroll
        for (int j = 0; j < 16; ++j) acc[j] = (f32x4){0.f, 0.f, 0.f, 0.f};

        float4 va = make_float4(0.f, 0.f, 0.f, 0.f);
        float4 vb = make_float4(0.f, 0.f, 0.f, 0.f);
        if (ap) { va = *(const float4*)ap; vb = *(const float4*)(ap + 4); }

        for (int kb = 0; kb < DD; kb += 32) {
            bf16x8 af;
            af[0] = (short)f2bf(va.x); af[1] = (short)f2bf(va.y);
            af[2] = (short)f2bf(va.z); af[3] = (short)f2bf(va.w);
            af[4] = (short)f2bf(vb.x); af[5] = (short)f2bf(vb.y);
            af[6] = (short)f2bf(vb.z); af[7] = (short)f2bf(vb.w);
            if (kb + 32 < DD && ap) {
                va = *(const float4*)(ap + kb + 32);
                vb = *(const float4*)(ap + kb + 36);
            }
#pragma unroll
            for (int j = 0; j < 16; ++j) {
                int n = j * 16 + (lane & 15);
                int bbyte = (n * 512 + (kb + g * 8) * 2) ^ ((n & 7) << 4);
                bf16x8 bfr = *(const bf16x8*)((const char*)Wt + bbyte);
                acc[j] = __builtin_amdgcn_mfma_f32_16x16x32_bf16(af, bfr, acc[j], 0, 0, 0);
            }
        }

#pragma unroll
        for (int j = 0; j < 16; ++j) {
            int col = j * 16 + (lane & 15);
#pragma unroll
            for (int r = 0; r < 4; ++r) {
                int row = row0 + wave * 16 + g * 4 + r;
                if (row < M) C[(size_t)row * DD + col] = f2bf(acc[j][r]);
            }
        }
    }
}

// ---------------- pull aggregation: half-wave edge split (8 gathers in flight/wave) ----------------
__global__ __launch_bounds__(256) void k_aggpull(const unsigned short* __restrict__ xwb,
                                                 const int* __restrict__ rowptr,
                                                 const unsigned* __restrict__ esw,
                                                 const int* __restrict__ degcnt,
                                                 const float* __restrict__ b,
                                                 unsigned short* __restrict__ aggb,
                                                 float* __restrict__ ps,
                                                 float* __restrict__ ps2, int N) {
    __shared__ float sred[4 * DD];
    __shared__ float qred[4 * DD];
    const int lane = threadIdx.x & 63;
    const int wave = threadIdx.x >> 6;
    const int half = lane >> 5;          // 0/1: alternate edges
    const int c = (lane & 31) * 8;       // 8 cols per lane, 32 lanes cover the row
    const int gw = (blockIdx.x * blockDim.x + threadIdx.x) >> 6;

    float bb[8];
#pragma unroll
    for (int i = 0; i < 8; ++i) bb[i] = b[c + i];

    float s[8], q[8];
#pragma unroll
    for (int i = 0; i < 8; ++i) { s[i] = 0.f; q[i] = 0.f; }

    for (int n = gw; n < N; n += AGG_WAVES) {
        float acc[8];
        if (half == 0) {
            float di = rsqrtf((float)(degcnt[n] + 1));
            float w0 = di * di;
            u16x8 v = *(const u16x8*)&xwb[(size_t)n * DD + c];
#pragma unroll
            for (int i = 0; i < 8; ++i) acc[i] = bf2f(v[i]) * w0 + bb[i];
        } else {
#pragma unroll
            for (int i = 0; i < 8; ++i) acc[i] = 0.f;
        }

        int j0 = rowptr[n], j1 = rowptr[n + 1];
        int j = j0 + half;
        // 4 edges in flight per half-wave => 8 per wave
        for (; j + 6 < j1; j += 8) {
            unsigned e0 = esw[j], e1 = esw[j + 2], e2 = esw[j + 4], e3 = esw[j + 6];
            u16x8 u0 = *(const u16x8*)&xwb[(size_t)(e0 & 0xFFFFu) * DD + c];
            u16x8 u1 = *(const u16x8*)&xwb[(size_t)(e1 & 0xFFFFu) * DD + c];
            u16x8 u2 = *(const u16x8*)&xwb[(size_t)(e2 & 0xFFFFu) * DD + c];
            u16x8 u3 = *(const u16x8*)&xwb[(size_t)(e3 & 0xFFFFu) * DD + c];
            float w0_ = bf2f((unsigned short)(e0 >> 16));
            float w1_ = bf2f((unsigned short)(e1 >> 16));
            float w2_ = bf2f((unsigned short)(e2 >> 16));
            float w3_ = bf2f((unsigned short)(e3 >> 16));
#pragma unroll
            for (int i = 0; i < 8; ++i)
                acc[i] += bf2f(u0[i]) * w0_ + bf2f(u1[i]) * w1_ +
                          bf2f(u2[i]) * w2_ + bf2f(u3[i]) * w3_;
        }
        for (; j < j1; j += 2) {
            unsigned e0 = esw[j];
            u16x8 u0 = *(const u16x8*)&xwb[(size_t)(e0 & 0xFFFFu) * DD + c];
            float w0_ = bf2f((unsigned short)(e0 >> 16));
#pragma unroll
            for (int i = 0; i < 8; ++i) acc[i] += bf2f(u0[i]) * w0_;
        }

        // combine halves (both end up with the total)
#pragma unroll
        for (int i = 0; i < 8; ++i) acc[i] += __shfl_xor(acc[i], 32);

        if (half == 0) {
            u16x8 o;
#pragma unroll
            for (int i = 0; i < 8; ++i) o[i] = f2bf(acc[i]);
            *(u16x8*)&aggb[(size_t)n * DD + c] = o;
#pragma unroll
            for (int i = 0; i < 8; ++i) { s[i] += acc[i]; q[i] += acc[i] * acc[i]; }
        }
    }

    if (half == 0) {
#pragma unroll
        for (int i = 0; i < 8; ++i) {
            sred[wave * DD + c + i] = s[i];
            qred[wave * DD + c + i] = q[i];
        }
    }
    __syncthreads();
    int d = threadIdx.x;
    float S = sred[d] + sred[DD + d] + sred[2 * DD + d] + sred[3 * DD + d];
    float Q = qred[d] + qred[DD + d] + qred[2 * DD + d] + qred[3 * DD + d];
    ps[(size_t)blockIdx.x * DD + d] = S;
    ps2[(size_t)blockIdx.x * DD + d] = Q;
}

// ---------------- per-block partials -> colsum/colsumsq (no atomics) ----------------
__global__ __launch_bounds__(256) void k_bnred(const float* __restrict__ ps,
                                               const float* __restrict__ ps2,
                                               float* __restrict__ colsum,
                                               float* __restrict__ colsumsq) {
    __shared__ float ss[256], qq[256];
    int cgrp = threadIdx.x & 3;
    int r = threadIdx.x >> 2;  // 0..63
    int col = blockIdx.x * 4 + cgrp;
    float s = 0.f, q = 0.f;
    for (int row = r; row < AGG_BLOCKS; row += 64) {
        s += ps[(size_t)row * DD + col];
        q += ps2[(size_t)row * DD + col];
    }
    ss[threadIdx.x] = s;
    qq[threadIdx.x] = q;
    __syncthreads();
    if (threadIdx.x < 4) {
        float S = 0.f, Q = 0.f;
        for (int k = threadIdx.x; k < 256; k += 4) { S += ss[k]; Q += qq[k]; }
        colsum[blockIdx.x * 4 + threadIdx.x] = S;
        colsumsq[blockIdx.x * 4 + threadIdx.x] = Q;
    }
}

// ---------------- BN-apply + ReLU + per-graph-slice pooled partials (no atomics) ----------------
__global__ __launch_bounds__(256) void k_pool(const unsigned short* __restrict__ aggb,
                                              const int* __restrict__ batch,
                                              const float* __restrict__ colsum,
                                              const float* __restrict__ colsumsq,
                                              const float* __restrict__ gamma,
                                              const float* __restrict__ beta,
                                              float* __restrict__ pools, int N) {
    int g = blockIdx.x / POOL_PARTS;
    int p = blockIdx.x % POOL_PARTS;
    int d = threadIdx.x;
    int lo = 0, hi = N;
    while (lo < hi) { int mid = (lo + hi) >> 1; if (batch[mid] < g) lo = mid + 1; else hi = mid; }
    int start = lo;
    lo = 0; hi = N;
    while (lo < hi) { int mid = (lo + hi) >> 1; if (batch[mid] < g + 1) lo = mid + 1; else hi = mid; }
    int len = lo - start;
    int s0 = start + (len * p) / POOL_PARTS;
    int s1 = start + (len * (p + 1)) / POOL_PARTS;

    float m = colsum[d] / (float)N;
    float var = colsumsq[d] / (float)N - m * m;
    float rs = rsqrtf(var + BN_EPS);
    float gm = gamma[d], bt = beta[d];
    float acc = 0.f;
    for (int n = s0; n < s1; ++n) {
        float a = bf2f(aggb[(size_t)n * DD + d]);
        acc += fmaxf(gm * (a - m) * rs + bt, 0.f);
    }
    pools[(size_t)blockIdx.x * DD + d] = acc;
}

// ---------------- head: count + partial-reduce + mean + FC + log_softmax ----------------
__global__ void k_head(const float* __restrict__ pools, const int* __restrict__ batch, int N,
                       const float* __restrict__ Wf, const float* __restrict__ bfv,
                       float* __restrict__ out) {
    int g = blockIdx.x;
    int lane = threadIdx.x;
    __shared__ float pm[DD];
    int lo = 0, hi = N;
    while (lo < hi) { int mid = (lo + hi) >> 1; if (batch[mid] < g) lo = mid + 1; else hi = mid; }
    int start = lo;
    lo = 0; hi = N;
    while (lo < hi) { int mid = (lo + hi) >> 1; if (batch[mid] < g + 1) lo = mid + 1; else hi = mid; }
    float cinv = 1.0f / fmaxf((float)(lo - start), 1.0f);

    for (int k = lane; k < DD; k += 64) {
        float s = 0.f;
#pragma unroll
        for (int p = 0; p < POOL_PARTS; ++p)
            s += pools[((size_t)g * POOL_PARTS + p) * DD + k];
        pm[k] = s * cinv;
    }
    __syncthreads();
    float logit = -INFINITY;
    if (lane < NCLS) {
        float s = bfv[lane];
        for (int k = 0; k < DD; ++k) s += pm[k] * Wf[lane * DD + k];
        logit = s;
    }
    float mx = logit;
#pragma unroll
    for (int off = 32; off; off >>= 1) mx = fmaxf(mx, __shfl_xor(mx, off));
    float ex = (lane < NCLS) ? expf(logit - mx) : 0.f;
    float sum = ex;
#pragma unroll
    for (int off = 32; off; off >>= 1) sum += __shfl_xor(sum, off);
    if (lane < NCLS) out[g * NCLS + lane] = logit - mx - logf(sum);
}

extern "C" void kernel_launch(void* const* d_in, const int* in_sizes, int n_in,
                              void* d_out, int out_size, void* d_ws, size_t ws_size,
                              hipStream_t stream) {
    const float* x     = (const float*)d_in[0];
    const int*   ei    = (const int*)d_in[1];
    const int*   batch = (const int*)d_in[2];
    const float* W     = (const float*)d_in[3];
    const float* b     = (const float*)d_in[4];
    const float* gamma = (const float*)d_in[5];
    const float* beta  = (const float*)d_in[6];
    const float* Wf    = (const float*)d_in[7];
    const float* bf    = (const float*)d_in[8];
    float* out = (float*)d_out;

    const int E = in_sizes[1] / 2;
    const int N = in_sizes[2];
    const int* src = ei;
    const int* dst = ei + E;

    size_t off = 0;
    auto alloc = [&](size_t bytes) {
        void* p = (char*)d_ws + off;
        off += (bytes + 255) & ~(size_t)255;
        return p;
    };
    int*   degcnt    = (int*)alloc((size_t)N * 4);   // zeroed (only memset)
    size_t zbytes = off;
    int*   rowptr    = (int*)alloc(((size_t)N + 1) * 4);
    int*   fillcur   = (int*)alloc((size_t)N * 4);
    unsigned* esw    = (unsigned*)alloc((size_t)E * 4);
    unsigned short* wtg  = (unsigned short*)alloc((size_t)DD * DD * 2);
    unsigned short* xwb  = (unsigned short*)alloc((size_t)N * DD * 2);
    unsigned short* aggb = (unsigned short*)alloc((size_t)N * DD * 2);
    float* ps        = (float*)alloc((size_t)AGG_BLOCKS * DD * 4);
    float* ps2       = (float*)alloc((size_t)AGG_BLOCKS * DD * 4);
    float* pools     = (float*)alloc((size_t)NGRAPH * POOL_PARTS * DD * 4);
    float* colsum    = (float*)alloc(DD * 4);
    float* colsumsq  = (float*)alloc(DD * 4);
    int*   bsum      = (int*)alloc(((size_t)N / SCAN_B + 2) * 4);

    hipMemsetAsync(degcnt, 0, zbytes, stream);

    k_degcount<<<(E + 255) / 256, 256, 0, stream>>>(dst, E, degcnt);

    int nblk = (N + SCAN_B - 1) / SCAN_B;
    k_scan1wt<<<nblk + DD, SCAN_B, 0, stream>>>(degcnt, N, nblk, rowptr, bsum, W, wtg);
    k_scan2<<<1, SCAN_B, 0, stream>>>(bsum, nblk, &rowptr[N]);
    k_scan3f<<<nblk, SCAN_B, 0, stream>>>(rowptr, N, bsum, fillcur);
    k_fill<<<(E + 255) / 256, 256, 0, stream>>>(src, dst, degcnt, fillcur, E, esw);

    int ntiles = (N + GBM - 1) / GBM;
    k_gemm_mfma<<<min(256, ntiles), 512, 0, stream>>>(x, wtg, xwb, N, ntiles);

    k_aggpull<<<AGG_BLOCKS, 256, 0, stream>>>(xwb, rowptr, esw, degcnt, b, aggb, ps, ps2, N);

    k_bnred<<<DD / 4, 256, 0, stream>>>(ps, ps2, colsum, colsumsq);
    k_pool<<<NGRAPH * POOL_PARTS, 256, 0, stream>>>(aggb, batch, colsum, colsumsq, gamma, beta,
                                                    pools, N);
    k_head<<<NGRAPH, 64, 0, stream>>>(pools, batch, N, Wf, bf, out);
}

// Round 12
// 228.142 us; speedup vs baseline: 1.6053x; 1.6053x over previous
//
#include <hip/hip_runtime.h>

#define DD 256
#define NGRAPH 64
#define NCLS 60
#define BN_EPS 1e-5f
#define SCAN_B 256
#define AGG_BLOCKS 2048
#define AGG_WAVES (AGG_BLOCKS * 4)
#define POOL_PARTS 16

typedef __attribute__((ext_vector_type(8))) short bf16x8;
typedef __attribute__((ext_vector_type(4))) float f32x4;

__device__ __forceinline__ unsigned short f2bf(float f) {
    union { float f; unsigned u; } v;
    v.f = f;
    unsigned r = v.u + 0x7FFFu + ((v.u >> 16) & 1u);  // RNE
    return (unsigned short)(r >> 16);
}
__device__ __forceinline__ float bf2f(unsigned short u) {
    union { unsigned u; float f; } v;
    v.u = ((unsigned)u) << 16;
    return v.f;
}

// ---------------- degree ----------------
__global__ void k_degcount(const int* __restrict__ dst, int E, int* __restrict__ degcnt) {
    int e = blockIdx.x * blockDim.x + threadIdx.x;
    if (e < E) atomicAdd(&degcnt[dst[e]], 1);
}

// ---------------- scan phase 1 (blocks 0..nblk-1) + W transpose (blocks nblk..nblk+255) ----------------
__global__ __launch_bounds__(256) void k_scan1wt(const int* __restrict__ in, int n, int nblk,
                                                 int* __restrict__ out, int* __restrict__ bsum,
                                                 const float* __restrict__ W,
                                                 unsigned short* __restrict__ Wt) {
    if (blockIdx.x >= nblk) {
        int col = blockIdx.x - nblk;          // 0..255: column of W -> row of Wt
        int k = threadIdx.x;
        Wt[col * DD + k] = f2bf(W[k * DD + col]);
        return;
    }
    __shared__ int sm[SCAN_B];
    int i = blockIdx.x * SCAN_B + threadIdx.x;
    int v = (i < n) ? in[i] : 0;
    sm[threadIdx.x] = v;
    __syncthreads();
    int acc = v;
    for (int off = 1; off < SCAN_B; off <<= 1) {
        int t = (threadIdx.x >= off) ? sm[threadIdx.x - off] : 0;
        __syncthreads();
        acc += t;
        sm[threadIdx.x] = acc;
        __syncthreads();
    }
    if (i < n) out[i] = acc - v;
    if (threadIdx.x == SCAN_B - 1) bsum[blockIdx.x] = acc;
}

__global__ void k_scan2(int* __restrict__ bsum, int nb, int* __restrict__ total) {
    __shared__ int sm[SCAN_B];
    __shared__ int carry;
    if (threadIdx.x == 0) carry = 0;
    __syncthreads();
    for (int base = 0; base < nb; base += SCAN_B) {
        int i = base + threadIdx.x;
        int v = (i < nb) ? bsum[i] : 0;
        sm[threadIdx.x] = v;
        __syncthreads();
        int acc = v;
        for (int off = 1; off < SCAN_B; off <<= 1) {
            int t = (threadIdx.x >= off) ? sm[threadIdx.x - off] : 0;
            __syncthreads();
            acc += t;
            sm[threadIdx.x] = acc;
            __syncthreads();
        }
        if (i < nb) bsum[i] = carry + acc - v;
        __syncthreads();
        if (threadIdx.x == SCAN_B - 1) carry += acc;
        __syncthreads();
    }
    if (threadIdx.x == 0 && total) *total = carry;
}

// scan phase 3: finalize rowptr and initialize fill cursors
__global__ void k_scan3f(int* __restrict__ rowptr, int n, const int* __restrict__ bsum,
                         int* __restrict__ fillcur) {
    int i = blockIdx.x * SCAN_B + threadIdx.x;
    if (i < n) {
        int v = rowptr[i] + bsum[blockIdx.x];
        rowptr[i] = v;
        fillcur[i] = v;
    }
}

// ---------------- CSR bucket fill: packed 4B (src:16 | norm_bf16:16) ----------------
__global__ void k_fill(const int* __restrict__ src, const int* __restrict__ dst,
                       const int* __restrict__ degcnt, int* __restrict__ fillcur,
                       int E, unsigned* __restrict__ esw) {
    int e = blockIdx.x * blockDim.x + threadIdx.x;
    if (e >= E) return;
    int s = src[e], d = dst[e];
    float w = rsqrtf((float)(degcnt[s] + 1)) * rsqrtf((float)(degcnt[d] + 1));
    int slot = atomicAdd(&fillcur[d], 1);
    esw[slot] = (unsigned)s | ((unsigned)f2bf(w) << 16);  // N < 65536
}

// ---------------- MFMA GEMM: 128x128 tile, 512 threads, 72KB LDS -> 2 blocks/CU ----------------
#define GBM 128
#define GBN 128
__global__ __launch_bounds__(512) void k_gemm_mfma(const float* __restrict__ A,
                                                   const unsigned short* __restrict__ Wtg,
                                                   unsigned short* __restrict__ C, int M) {
    __shared__ short Wt[GBN * 256];  // [n][k] bf16, XOR-swizzled, 64 KB
    __shared__ short At[GBM * 32];   // [row][k] bf16 per k-step, swizzled, 8 KB
    const int tid = threadIdx.x;
    const int wave = tid >> 6;
    const int lane = tid & 63;
    const int row0 = blockIdx.x * GBM;
    const int n0 = blockIdx.y * GBN;

    // stage Wt slice: 128 rows x 32 chunks of 16B = 4096 chunks, 8 per thread
#pragma unroll
    for (int i = 0; i < 8; ++i) {
        int cid = tid + i * 512;
        int n = cid >> 5;
        int k0 = (cid & 31) * 8;
        bf16x8 pk = *(const bf16x8*)&Wtg[(size_t)(n0 + n) * DD + k0];
        int byte = (n * 512 + k0 * 2) ^ ((n & 7) << 4);
        *(bf16x8*)((char*)Wt + byte) = pk;
    }

    f32x4 acc[8];
#pragma unroll
    for (int j = 0; j < 8; ++j) acc[j] = (f32x4){0.f, 0.f, 0.f, 0.f};

    const int arow = tid >> 2;        // 0..127
    const int aslot = tid & 3;        // 0..3 (8 k's each)
    const int grow = row0 + arow;
    const int frow = wave * 16 + (lane & 15);   // 0..127
    const int g = lane >> 4;
    const int abyte_st = (arow * 64 + aslot * 16) ^ ((arow & 3) << 4);
    const float* ap = (grow < M) ? &A[(size_t)grow * DD + aslot * 8] : nullptr;

    float4 va = make_float4(0.f, 0.f, 0.f, 0.f);
    float4 vb = make_float4(0.f, 0.f, 0.f, 0.f);
    if (ap) { va = *(const float4*)ap; vb = *(const float4*)(ap + 4); }

    for (int kb = 0; kb < DD; kb += 32) {
        __syncthreads();  // previous compute done reading At
        {
            bf16x8 pk;
            pk[0] = (short)f2bf(va.x); pk[1] = (short)f2bf(va.y);
            pk[2] = (short)f2bf(va.z); pk[3] = (short)f2bf(va.w);
            pk[4] = (short)f2bf(vb.x); pk[5] = (short)f2bf(vb.y);
            pk[6] = (short)f2bf(vb.z); pk[7] = (short)f2bf(vb.w);
            *(bf16x8*)((char*)At + abyte_st) = pk;
        }
        __syncthreads();  // At ready

        if (kb + 32 < DD && ap) {
            va = *(const float4*)(ap + kb + 32);
            vb = *(const float4*)(ap + kb + 36);
        }

        int abyte = (frow * 64 + g * 16) ^ ((frow & 3) << 4);
        bf16x8 af = *(const bf16x8*)((const char*)At + abyte);
#pragma unroll
        for (int j = 0; j < 8; ++j) {
            int n = j * 16 + (lane & 15);
            int bbyte = (n * 512 + (kb + g * 8) * 2) ^ ((n & 7) << 4);
            bf16x8 bfr = *(const bf16x8*)((const char*)Wt + bbyte);
            acc[j] = __builtin_amdgcn_mfma_f32_16x16x32_bf16(af, bfr, acc[j], 0, 0, 0);
        }
    }

#pragma unroll
    for (int j = 0; j < 8; ++j) {
        int col = n0 + j * 16 + (lane & 15);
#pragma unroll
        for (int r = 0; r < 4; ++r) {
            int row = row0 + wave * 16 + g * 4 + r;
            if (row < M) C[(size_t)row * DD + col] = f2bf(acc[j][r]);
        }
    }
}

// ---------------- pull aggregation (persistent, full row/wave) + BN partials ----------------
__global__ __launch_bounds__(256) void k_aggpull(const unsigned short* __restrict__ xwb,
                                                 const int* __restrict__ rowptr,
                                                 const unsigned* __restrict__ esw,
                                                 const int* __restrict__ degcnt,
                                                 const float* __restrict__ b,
                                                 unsigned short* __restrict__ aggb,
                                                 float* __restrict__ ps,
                                                 float* __restrict__ ps2, int N) {
    __shared__ float sred[4 * DD];
    __shared__ float qred[4 * DD];
    const int lane = threadIdx.x & 63;
    const int wave = threadIdx.x >> 6;
    const int c = lane * 4;
    const int gw = (blockIdx.x * blockDim.x + threadIdx.x) >> 6;
    const float4 bb = *(const float4*)&b[c];

    float s0 = 0.f, s1 = 0.f, s2 = 0.f, s3 = 0.f;
    float q0 = 0.f, q1 = 0.f, q2 = 0.f, q3 = 0.f;

    for (int n = gw; n < N; n += AGG_WAVES) {
        float di = rsqrtf((float)(degcnt[n] + 1));
        float w0 = di * di;
        ushort4 v = *(const ushort4*)&xwb[(size_t)n * DD + c];
        float4 acc = make_float4(bf2f(v.x) * w0, bf2f(v.y) * w0, bf2f(v.z) * w0, bf2f(v.w) * w0);

        int j0 = rowptr[n], j1 = rowptr[n + 1];
        int j = j0;
        for (; j + 3 < j1; j += 4) {
            unsigned e0 = esw[j + 0], e1 = esw[j + 1], e2 = esw[j + 2], e3 = esw[j + 3];
            ushort4 u0 = *(const ushort4*)&xwb[(size_t)(e0 & 0xFFFFu) * DD + c];
            ushort4 u1 = *(const ushort4*)&xwb[(size_t)(e1 & 0xFFFFu) * DD + c];
            ushort4 u2 = *(const ushort4*)&xwb[(size_t)(e2 & 0xFFFFu) * DD + c];
            ushort4 u3 = *(const ushort4*)&xwb[(size_t)(e3 & 0xFFFFu) * DD + c];
            float wa = bf2f((unsigned short)(e0 >> 16));
            float wb = bf2f((unsigned short)(e1 >> 16));
            float wc = bf2f((unsigned short)(e2 >> 16));
            float wd = bf2f((unsigned short)(e3 >> 16));
            acc.x += bf2f(u0.x) * wa + bf2f(u1.x) * wb + bf2f(u2.x) * wc + bf2f(u3.x) * wd;
            acc.y += bf2f(u0.y) * wa + bf2f(u1.y) * wb + bf2f(u2.y) * wc + bf2f(u3.y) * wd;
            acc.z += bf2f(u0.z) * wa + bf2f(u1.z) * wb + bf2f(u2.z) * wc + bf2f(u3.z) * wd;
            acc.w += bf2f(u0.w) * wa + bf2f(u1.w) * wb + bf2f(u2.w) * wc + bf2f(u3.w) * wd;
        }
        for (; j < j1; ++j) {
            unsigned e0 = esw[j];
            float wa = bf2f((unsigned short)(e0 >> 16));
            ushort4 u0 = *(const ushort4*)&xwb[(size_t)(e0 & 0xFFFFu) * DD + c];
            acc.x += bf2f(u0.x) * wa;
            acc.y += bf2f(u0.y) * wa;
            acc.z += bf2f(u0.z) * wa;
            acc.w += bf2f(u0.w) * wa;
        }
        acc.x += bb.x;
        acc.y += bb.y;
        acc.z += bb.z;
        acc.w += bb.w;

        ushort4 o;
        o.x = f2bf(acc.x); o.y = f2bf(acc.y); o.z = f2bf(acc.z); o.w = f2bf(acc.w);
        *(ushort4*)&aggb[(size_t)n * DD + c] = o;

        s0 += acc.x; q0 += acc.x * acc.x;
        s1 += acc.y; q1 += acc.y * acc.y;
        s2 += acc.z; q2 += acc.z * acc.z;
        s3 += acc.w; q3 += acc.w * acc.w;
    }

    f32x4 sv = {s0, s1, s2, s3};
    f32x4 qv = {q0, q1, q2, q3};
    *(f32x4*)&sred[wave * DD + c] = sv;
    *(f32x4*)&qred[wave * DD + c] = qv;
    __syncthreads();
    int d = threadIdx.x;
    float s = sred[d] + sred[DD + d] + sred[2 * DD + d] + sred[3 * DD + d];
    float q = qred[d] + qred[DD + d] + qred[2 * DD + d] + qred[3 * DD + d];
    ps[(size_t)blockIdx.x * DD + d] = s;
    ps2[(size_t)blockIdx.x * DD + d] = q;
}

// ---------------- per-block partials -> colsum/colsumsq (no atomics) ----------------
__global__ __launch_bounds__(256) void k_bnred(const float* __restrict__ ps,
                                               const float* __restrict__ ps2,
                                               float* __restrict__ colsum,
                                               float* __restrict__ colsumsq) {
    __shared__ float ss[256], qq[256];
    int cgrp = threadIdx.x & 3;
    int r = threadIdx.x >> 2;  // 0..63
    int col = blockIdx.x * 4 + cgrp;
    float s = 0.f, q = 0.f;
    for (int row = r; row < AGG_BLOCKS; row += 64) {
        s += ps[(size_t)row * DD + col];
        q += ps2[(size_t)row * DD + col];
    }
    ss[threadIdx.x] = s;
    qq[threadIdx.x] = q;
    __syncthreads();
    if (threadIdx.x < 4) {
        float S = 0.f, Q = 0.f;
        for (int k = threadIdx.x; k < 256; k += 4) { S += ss[k]; Q += qq[k]; }
        colsum[blockIdx.x * 4 + threadIdx.x] = S;
        colsumsq[blockIdx.x * 4 + threadIdx.x] = Q;
    }
}

// ---------------- BN-apply + ReLU + per-graph-slice pooled partials (no atomics) ----------------
__global__ __launch_bounds__(256) void k_pool(const unsigned short* __restrict__ aggb,
                                              const int* __restrict__ batch,
                                              const float* __restrict__ colsum,
                                              const float* __restrict__ colsumsq,
                                              const float* __restrict__ gamma,
                                              const float* __restrict__ beta,
                                              float* __restrict__ pools, int N) {
    int g = blockIdx.x / POOL_PARTS;
    int p = blockIdx.x % POOL_PARTS;
    int d = threadIdx.x;
    int lo = 0, hi = N;
    while (lo < hi) { int mid = (lo + hi) >> 1; if (batch[mid] < g) lo = mid + 1; else hi = mid; }
    int start = lo;
    lo = 0; hi = N;
    while (lo < hi) { int mid = (lo + hi) >> 1; if (batch[mid] < g + 1) lo = mid + 1; else hi = mid; }
    int len = lo - start;
    int s0 = start + (len * p) / POOL_PARTS;
    int s1 = start + (len * (p + 1)) / POOL_PARTS;

    float m = colsum[d] / (float)N;
    float var = colsumsq[d] / (float)N - m * m;
    float rs = rsqrtf(var + BN_EPS);
    float gm = gamma[d], bt = beta[d];
    float acc = 0.f;
    for (int n = s0; n < s1; ++n) {
        float a = bf2f(aggb[(size_t)n * DD + d]);
        acc += fmaxf(gm * (a - m) * rs + bt, 0.f);
    }
    pools[(size_t)blockIdx.x * DD + d] = acc;
}

// ---------------- head: count + partial-reduce + mean + FC + log_softmax ----------------
__global__ void k_head(const float* __restrict__ pools, const int* __restrict__ batch, int N,
                       const float* __restrict__ Wf, const float* __restrict__ bfv,
                       float* __restrict__ out) {
    int g = blockIdx.x;
    int lane = threadIdx.x;
    __shared__ float pm[DD];
    int lo = 0, hi = N;
    while (lo < hi) { int mid = (lo + hi) >> 1; if (batch[mid] < g) lo = mid + 1; else hi = mid; }
    int start = lo;
    lo = 0; hi = N;
    while (lo < hi) { int mid = (lo + hi) >> 1; if (batch[mid] < g + 1) lo = mid + 1; else hi = mid; }
    float cinv = 1.0f / fmaxf((float)(lo - start), 1.0f);

    for (int k = lane; k < DD; k += 64) {
        float s = 0.f;
#pragma unroll
        for (int p = 0; p < POOL_PARTS; ++p)
            s += pools[((size_t)g * POOL_PARTS + p) * DD + k];
        pm[k] = s * cinv;
    }
    __syncthreads();
    float logit = -INFINITY;
    if (lane < NCLS) {
        float s = bfv[lane];
        for (int k = 0; k < DD; ++k) s += pm[k] * Wf[lane * DD + k];
        logit = s;
    }
    float mx = logit;
#pragma unroll
    for (int off = 32; off; off >>= 1) mx = fmaxf(mx, __shfl_xor(mx, off));
    float ex = (lane < NCLS) ? expf(logit - mx) : 0.f;
    float sum = ex;
#pragma unroll
    for (int off = 32; off; off >>= 1) sum += __shfl_xor(sum, off);
    if (lane < NCLS) out[g * NCLS + lane] = logit - mx - logf(sum);
}

extern "C" void kernel_launch(void* const* d_in, const int* in_sizes, int n_in,
                              void* d_out, int out_size, void* d_ws, size_t ws_size,
                              hipStream_t stream) {
    const float* x     = (const float*)d_in[0];
    const int*   ei    = (const int*)d_in[1];
    const int*   batch = (const int*)d_in[2];
    const float* W     = (const float*)d_in[3];
    const float* b     = (const float*)d_in[4];
    const float* gamma = (const float*)d_in[5];
    const float* beta  = (const float*)d_in[6];
    const float* Wf    = (const float*)d_in[7];
    const float* bf    = (const float*)d_in[8];
    float* out = (float*)d_out;

    const int E = in_sizes[1] / 2;
    const int N = in_sizes[2];
    const int* src = ei;
    const int* dst = ei + E;

    size_t off = 0;
    auto alloc = [&](size_t bytes) {
        void* p = (char*)d_ws + off;
        off += (bytes + 255) & ~(size_t)255;
        return p;
    };
    int*   degcnt    = (int*)alloc((size_t)N * 4);   // zeroed (only memset)
    size_t zbytes = off;
    int*   rowptr    = (int*)alloc(((size_t)N + 1) * 4);
    int*   fillcur   = (int*)alloc((size_t)N * 4);
    unsigned* esw    = (unsigned*)alloc((size_t)E * 4);
    unsigned short* wtg  = (unsigned short*)alloc((size_t)DD * DD * 2);
    unsigned short* xwb  = (unsigned short*)alloc((size_t)N * DD * 2);
    unsigned short* aggb = (unsigned short*)alloc((size_t)N * DD * 2);
    float* ps        = (float*)alloc((size_t)AGG_BLOCKS * DD * 4);
    float* ps2       = (float*)alloc((size_t)AGG_BLOCKS * DD * 4);
    float* pools     = (float*)alloc((size_t)NGRAPH * POOL_PARTS * DD * 4);
    float* colsum    = (float*)alloc(DD * 4);
    float* colsumsq  = (float*)alloc(DD * 4);
    int*   bsum      = (int*)alloc(((size_t)N / SCAN_B + 2) * 4);

    hipMemsetAsync(degcnt, 0, zbytes, stream);

    k_degcount<<<(E + 255) / 256, 256, 0, stream>>>(dst, E, degcnt);

    int nblk = (N + SCAN_B - 1) / SCAN_B;
    k_scan1wt<<<nblk + DD, SCAN_B, 0, stream>>>(degcnt, N, nblk, rowptr, bsum, W, wtg);
    k_scan2<<<1, SCAN_B, 0, stream>>>(bsum, nblk, &rowptr[N]);
    k_scan3f<<<nblk, SCAN_B, 0, stream>>>(rowptr, N, bsum, fillcur);
    k_fill<<<(E + 255) / 256, 256, 0, stream>>>(src, dst, degcnt, fillcur, E, esw);

    dim3 ggrid((N + GBM - 1) / GBM, DD / GBN);
    k_gemm_mfma<<<ggrid, 512, 0, stream>>>(x, wtg, xwb, N);

    k_aggpull<<<AGG_BLOCKS, 256, 0, stream>>>(xwb, rowptr, esw, degcnt, b, aggb, ps, ps2, N);

    k_bnred<<<DD / 4, 256, 0, stream>>>(ps, ps2, colsum, colsumsq);
    k_pool<<<NGRAPH * POOL_PARTS, 256, 0, stream>>>(aggb, batch, colsum, colsumsq, gamma, beta,
                                                    pools, N);
    k_head<<<NGRAPH, 64, 0, stream>>>(pools, batch, N, Wf, bf, out);
}

// Round 13
// 220.437 us; speedup vs baseline: 1.6614x; 1.0350x over previous
//
#include <hip/hip_runtime.h>

#define DD 256
#define NGRAPH 64
#define NCLS 60
#define BN_EPS 1e-5f
#define SCAN_B 256
#define AGG_BLOCKS 2048
#define AGG_WAVES (AGG_BLOCKS * 4)
#define POOL_PARTS 16

typedef __attribute__((ext_vector_type(8))) short bf16x8;
typedef __attribute__((ext_vector_type(4))) float f32x4;

__device__ __forceinline__ unsigned short f2bf(float f) {
    union { float f; unsigned u; } v;
    v.f = f;
    unsigned r = v.u + 0x7FFFu + ((v.u >> 16) & 1u);  // RNE
    return (unsigned short)(r >> 16);
}
__device__ __forceinline__ float bf2f(unsigned short u) {
    union { unsigned u; float f; } v;
    v.u = ((unsigned)u) << 16;
    return v.f;
}

// ---------------- fused: degree count + x->bf16 convert ----------------
__global__ void k_degxconv(const int* __restrict__ dst, int E, int* __restrict__ degcnt,
                           const float* __restrict__ x, unsigned short* __restrict__ xb,
                           int nDeg, int nconv8) {
    if (blockIdx.x < nDeg) {
        int e = blockIdx.x * blockDim.x + threadIdx.x;
        if (e < E) atomicAdd(&degcnt[dst[e]], 1);
        return;
    }
    int i = (blockIdx.x - nDeg) * blockDim.x + threadIdx.x;  // 8 floats each
    if (i >= nconv8) return;
    const float4* p = (const float4*)&x[(size_t)i * 8];
    float4 a = p[0], c = p[1];
    bf16x8 o;
    o[0] = (short)f2bf(a.x); o[1] = (short)f2bf(a.y);
    o[2] = (short)f2bf(a.z); o[3] = (short)f2bf(a.w);
    o[4] = (short)f2bf(c.x); o[5] = (short)f2bf(c.y);
    o[6] = (short)f2bf(c.z); o[7] = (short)f2bf(c.w);
    *(bf16x8*)&xb[(size_t)i * 8] = o;
}

// ---------------- scan phase 1 (blocks 0..nblk-1) + W transpose (blocks nblk..nblk+255) ----------------
__global__ __launch_bounds__(256) void k_scan1wt(const int* __restrict__ in, int n, int nblk,
                                                 int* __restrict__ out, int* __restrict__ bsum,
                                                 const float* __restrict__ W,
                                                 unsigned short* __restrict__ Wt) {
    if (blockIdx.x >= nblk) {
        int col = blockIdx.x - nblk;          // 0..255: column of W -> row of Wt
        int k = threadIdx.x;
        Wt[col * DD + k] = f2bf(W[k * DD + col]);
        return;
    }
    __shared__ int sm[SCAN_B];
    int i = blockIdx.x * SCAN_B + threadIdx.x;
    int v = (i < n) ? in[i] : 0;
    sm[threadIdx.x] = v;
    __syncthreads();
    int acc = v;
    for (int off = 1; off < SCAN_B; off <<= 1) {
        int t = (threadIdx.x >= off) ? sm[threadIdx.x - off] : 0;
        __syncthreads();
        acc += t;
        sm[threadIdx.x] = acc;
        __syncthreads();
    }
    if (i < n) out[i] = acc - v;
    if (threadIdx.x == SCAN_B - 1) bsum[blockIdx.x] = acc;
}

__global__ void k_scan2(int* __restrict__ bsum, int nb, int* __restrict__ total) {
    __shared__ int sm[SCAN_B];
    __shared__ int carry;
    if (threadIdx.x == 0) carry = 0;
    __syncthreads();
    for (int base = 0; base < nb; base += SCAN_B) {
        int i = base + threadIdx.x;
        int v = (i < nb) ? bsum[i] : 0;
        sm[threadIdx.x] = v;
        __syncthreads();
        int acc = v;
        for (int off = 1; off < SCAN_B; off <<= 1) {
            int t = (threadIdx.x >= off) ? sm[threadIdx.x - off] : 0;
            __syncthreads();
            acc += t;
            sm[threadIdx.x] = acc;
            __syncthreads();
        }
        if (i < nb) bsum[i] = carry + acc - v;
        __syncthreads();
        if (threadIdx.x == SCAN_B - 1) carry += acc;
        __syncthreads();
    }
    if (threadIdx.x == 0 && total) *total = carry;
}

// scan phase 3: finalize rowptr and initialize fill cursors
__global__ void k_scan3f(int* __restrict__ rowptr, int n, const int* __restrict__ bsum,
                         int* __restrict__ fillcur) {
    int i = blockIdx.x * SCAN_B + threadIdx.x;
    if (i < n) {
        int v = rowptr[i] + bsum[blockIdx.x];
        rowptr[i] = v;
        fillcur[i] = v;
    }
}

// ---------------- fused: MFMA GEMM (bf16 A) + CSR fill ----------------
// gemm blocks [0, nGemm): 128x128 tile, 512 threads, 72KB LDS
// fill blocks [nGemm, ...): one edge per thread
#define GBM 128
#define GBN 128
__global__ __launch_bounds__(512) void k_gemmfill(const unsigned short* __restrict__ xb,
                                                  const unsigned short* __restrict__ Wtg,
                                                  unsigned short* __restrict__ C, int M,
                                                  int nGemm,
                                                  const int* __restrict__ src,
                                                  const int* __restrict__ dst,
                                                  const int* __restrict__ degcnt,
                                                  int* __restrict__ fillcur, int E,
                                                  unsigned* __restrict__ esw) {
    __shared__ short Wt[GBN * 256];  // 64 KB
    __shared__ short At[GBM * 32];   // 8 KB
    if (blockIdx.x >= nGemm) {
        int e = (blockIdx.x - nGemm) * 512 + threadIdx.x;
        if (e >= E) return;
        int s = src[e], d = dst[e];
        float w = rsqrtf((float)(degcnt[s] + 1)) * rsqrtf((float)(degcnt[d] + 1));
        int slot = atomicAdd(&fillcur[d], 1);
        esw[slot] = (unsigned)s | ((unsigned)f2bf(w) << 16);  // N < 65536
        return;
    }

    const int tid = threadIdx.x;
    const int wave = tid >> 6;
    const int lane = tid & 63;
    const int row0 = (blockIdx.x >> 1) * GBM;
    const int n0 = (blockIdx.x & 1) * GBN;

    // stage Wt slice: 4096 chunks of 16B, 8 per thread
#pragma unroll
    for (int i = 0; i < 8; ++i) {
        int cid = tid + i * 512;
        int n = cid >> 5;
        int k0 = (cid & 31) * 8;
        bf16x8 pk = *(const bf16x8*)&Wtg[(size_t)(n0 + n) * DD + k0];
        int byte = (n * 512 + k0 * 2) ^ ((n & 7) << 4);
        *(bf16x8*)((char*)Wt + byte) = pk;
    }

    f32x4 acc[8];
#pragma unroll
    for (int j = 0; j < 8; ++j) acc[j] = (f32x4){0.f, 0.f, 0.f, 0.f};

    const int arow = tid >> 2;        // 0..127
    const int aslot = tid & 3;        // 0..3 (8 k's each)
    const int grow = row0 + arow;
    const int frow = wave * 16 + (lane & 15);   // 0..127
    const int g = lane >> 4;
    const int abyte_st = (arow * 64 + aslot * 16) ^ ((arow & 3) << 4);
    const unsigned short* ap = (grow < M) ? &xb[(size_t)grow * DD + aslot * 8] : nullptr;

    bf16x8 av = (bf16x8){0, 0, 0, 0, 0, 0, 0, 0};
    if (ap) av = *(const bf16x8*)ap;

    for (int kb = 0; kb < DD; kb += 32) {
        __syncthreads();  // previous compute done reading At
        *(bf16x8*)((char*)At + abyte_st) = av;
        __syncthreads();  // At ready

        if (kb + 32 < DD && ap) av = *(const bf16x8*)(ap + kb + 32);

        int abyte = (frow * 64 + g * 16) ^ ((frow & 3) << 4);
        bf16x8 af = *(const bf16x8*)((const char*)At + abyte);
#pragma unroll
        for (int j = 0; j < 8; ++j) {
            int n = j * 16 + (lane & 15);
            int bbyte = (n * 512 + (kb + g * 8) * 2) ^ ((n & 7) << 4);
            bf16x8 bfr = *(const bf16x8*)((const char*)Wt + bbyte);
            acc[j] = __builtin_amdgcn_mfma_f32_16x16x32_bf16(af, bfr, acc[j], 0, 0, 0);
        }
    }

#pragma unroll
    for (int j = 0; j < 8; ++j) {
        int col = n0 + j * 16 + (lane & 15);
#pragma unroll
        for (int r = 0; r < 4; ++r) {
            int row = row0 + wave * 16 + g * 4 + r;
            if (row < M) C[(size_t)row * DD + col] = f2bf(acc[j][r]);
        }
    }
}

// ---------------- pull aggregation (persistent, full row/wave) + BN partials ----------------
__global__ __launch_bounds__(256) void k_aggpull(const unsigned short* __restrict__ xwb,
                                                 const int* __restrict__ rowptr,
                                                 const unsigned* __restrict__ esw,
                                                 const int* __restrict__ degcnt,
                                                 const float* __restrict__ b,
                                                 unsigned short* __restrict__ aggb,
                                                 float* __restrict__ ps,
                                                 float* __restrict__ ps2, int N) {
    __shared__ float sred[4 * DD];
    __shared__ float qred[4 * DD];
    const int lane = threadIdx.x & 63;
    const int wave = threadIdx.x >> 6;
    const int c = lane * 4;
    const int gw = (blockIdx.x * blockDim.x + threadIdx.x) >> 6;
    const float4 bb = *(const float4*)&b[c];

    float s0 = 0.f, s1 = 0.f, s2 = 0.f, s3 = 0.f;
    float q0 = 0.f, q1 = 0.f, q2 = 0.f, q3 = 0.f;

    for (int n = gw; n < N; n += AGG_WAVES) {
        float di = rsqrtf((float)(degcnt[n] + 1));
        float w0 = di * di;
        ushort4 v = *(const ushort4*)&xwb[(size_t)n * DD + c];
        float4 acc = make_float4(bf2f(v.x) * w0, bf2f(v.y) * w0, bf2f(v.z) * w0, bf2f(v.w) * w0);

        int j0 = rowptr[n], j1 = rowptr[n + 1];
        int j = j0;
        for (; j + 3 < j1; j += 4) {
            unsigned e0 = esw[j + 0], e1 = esw[j + 1], e2 = esw[j + 2], e3 = esw[j + 3];
            ushort4 u0 = *(const ushort4*)&xwb[(size_t)(e0 & 0xFFFFu) * DD + c];
            ushort4 u1 = *(const ushort4*)&xwb[(size_t)(e1 & 0xFFFFu) * DD + c];
            ushort4 u2 = *(const ushort4*)&xwb[(size_t)(e2 & 0xFFFFu) * DD + c];
            ushort4 u3 = *(const ushort4*)&xwb[(size_t)(e3 & 0xFFFFu) * DD + c];
            float wa = bf2f((unsigned short)(e0 >> 16));
            float wb = bf2f((unsigned short)(e1 >> 16));
            float wc = bf2f((unsigned short)(e2 >> 16));
            float wd = bf2f((unsigned short)(e3 >> 16));
            acc.x += bf2f(u0.x) * wa + bf2f(u1.x) * wb + bf2f(u2.x) * wc + bf2f(u3.x) * wd;
            acc.y += bf2f(u0.y) * wa + bf2f(u1.y) * wb + bf2f(u2.y) * wc + bf2f(u3.y) * wd;
            acc.z += bf2f(u0.z) * wa + bf2f(u1.z) * wb + bf2f(u2.z) * wc + bf2f(u3.z) * wd;
            acc.w += bf2f(u0.w) * wa + bf2f(u1.w) * wb + bf2f(u2.w) * wc + bf2f(u3.w) * wd;
        }
        for (; j < j1; ++j) {
            unsigned e0 = esw[j];
            float wa = bf2f((unsigned short)(e0 >> 16));
            ushort4 u0 = *(const ushort4*)&xwb[(size_t)(e0 & 0xFFFFu) * DD + c];
            acc.x += bf2f(u0.x) * wa;
            acc.y += bf2f(u0.y) * wa;
            acc.z += bf2f(u0.z) * wa;
            acc.w += bf2f(u0.w) * wa;
        }
        acc.x += bb.x;
        acc.y += bb.y;
        acc.z += bb.z;
        acc.w += bb.w;

        ushort4 o;
        o.x = f2bf(acc.x); o.y = f2bf(acc.y); o.z = f2bf(acc.z); o.w = f2bf(acc.w);
        *(ushort4*)&aggb[(size_t)n * DD + c] = o;

        s0 += acc.x; q0 += acc.x * acc.x;
        s1 += acc.y; q1 += acc.y * acc.y;
        s2 += acc.z; q2 += acc.z * acc.z;
        s3 += acc.w; q3 += acc.w * acc.w;
    }

    f32x4 sv = {s0, s1, s2, s3};
    f32x4 qv = {q0, q1, q2, q3};
    *(f32x4*)&sred[wave * DD + c] = sv;
    *(f32x4*)&qred[wave * DD + c] = qv;
    __syncthreads();
    int d = threadIdx.x;
    float s = sred[d] + sred[DD + d] + sred[2 * DD + d] + sred[3 * DD + d];
    float q = qred[d] + qred[DD + d] + qred[2 * DD + d] + qred[3 * DD + d];
    ps[(size_t)blockIdx.x * DD + d] = s;
    ps2[(size_t)blockIdx.x * DD + d] = q;
}

// ---------------- per-block partials -> colsum/colsumsq (no atomics) ----------------
__global__ __launch_bounds__(256) void k_bnred(const float* __restrict__ ps,
                                               const float* __restrict__ ps2,
                                               float* __restrict__ colsum,
                                               float* __restrict__ colsumsq) {
    __shared__ float ss[256], qq[256];
    int cgrp = threadIdx.x & 3;
    int r = threadIdx.x >> 2;  // 0..63
    int col = blockIdx.x * 4 + cgrp;
    float s = 0.f, q = 0.f;
    for (int row = r; row < AGG_BLOCKS; row += 64) {
        s += ps[(size_t)row * DD + col];
        q += ps2[(size_t)row * DD + col];
    }
    ss[threadIdx.x] = s;
    qq[threadIdx.x] = q;
    __syncthreads();
    if (threadIdx.x < 4) {
        float S = 0.f, Q = 0.f;
        for (int k = threadIdx.x; k < 256; k += 4) { S += ss[k]; Q += qq[k]; }
        colsum[blockIdx.x * 4 + threadIdx.x] = S;
        colsumsq[blockIdx.x * 4 + threadIdx.x] = Q;
    }
}

// ---------------- BN-apply + ReLU + per-graph-slice pooled partials (no atomics) ----------------
__global__ __launch_bounds__(256) void k_pool(const unsigned short* __restrict__ aggb,
                                              const int* __restrict__ batch,
                                              const float* __restrict__ colsum,
                                              const float* __restrict__ colsumsq,
                                              const float* __restrict__ gamma,
                                              const float* __restrict__ beta,
                                              float* __restrict__ pools, int N) {
    int g = blockIdx.x / POOL_PARTS;
    int p = blockIdx.x % POOL_PARTS;
    int d = threadIdx.x;
    int lo = 0, hi = N;
    while (lo < hi) { int mid = (lo + hi) >> 1; if (batch[mid] < g) lo = mid + 1; else hi = mid; }
    int start = lo;
    lo = 0; hi = N;
    while (lo < hi) { int mid = (lo + hi) >> 1; if (batch[mid] < g + 1) lo = mid + 1; else hi = mid; }
    int len = lo - start;
    int s0 = start + (len * p) / POOL_PARTS;
    int s1 = start + (len * (p + 1)) / POOL_PARTS;

    float m = colsum[d] / (float)N;
    float var = colsumsq[d] / (float)N - m * m;
    float rs = rsqrtf(var + BN_EPS);
    float gm = gamma[d], bt = beta[d];
    float acc = 0.f;
    for (int n = s0; n < s1; ++n) {
        float a = bf2f(aggb[(size_t)n * DD + d]);
        acc += fmaxf(gm * (a - m) * rs + bt, 0.f);
    }
    pools[(size_t)blockIdx.x * DD + d] = acc;
}

// ---------------- head: count + partial-reduce + mean + FC + log_softmax ----------------
__global__ void k_head(const float* __restrict__ pools, const int* __restrict__ batch, int N,
                       const float* __restrict__ Wf, const float* __restrict__ bfv,
                       float* __restrict__ out) {
    int g = blockIdx.x;
    int lane = threadIdx.x;
    __shared__ float pm[DD];
    int lo = 0, hi = N;
    while (lo < hi) { int mid = (lo + hi) >> 1; if (batch[mid] < g) lo = mid + 1; else hi = mid; }
    int start = lo;
    lo = 0; hi = N;
    while (lo < hi) { int mid = (lo + hi) >> 1; if (batch[mid] < g + 1) lo = mid + 1; else hi = mid; }
    float cinv = 1.0f / fmaxf((float)(lo - start), 1.0f);

    for (int k = lane; k < DD; k += 64) {
        float s = 0.f;
#pragma unroll
        for (int p = 0; p < POOL_PARTS; ++p)
            s += pools[((size_t)g * POOL_PARTS + p) * DD + k];
        pm[k] = s * cinv;
    }
    __syncthreads();
    float logit = -INFINITY;
    if (lane < NCLS) {
        float s = bfv[lane];
        for (int k = 0; k < DD; ++k) s += pm[k] * Wf[lane * DD + k];
        logit = s;
    }
    float mx = logit;
#pragma unroll
    for (int off = 32; off; off >>= 1) mx = fmaxf(mx, __shfl_xor(mx, off));
    float ex = (lane < NCLS) ? expf(logit - mx) : 0.f;
    float sum = ex;
#pragma unroll
    for (int off = 32; off; off >>= 1) sum += __shfl_xor(sum, off);
    if (lane < NCLS) out[g * NCLS + lane] = logit - mx - logf(sum);
}

extern "C" void kernel_launch(void* const* d_in, const int* in_sizes, int n_in,
                              void* d_out, int out_size, void* d_ws, size_t ws_size,
                              hipStream_t stream) {
    const float* x     = (const float*)d_in[0];
    const int*   ei    = (const int*)d_in[1];
    const int*   batch = (const int*)d_in[2];
    const float* W     = (const float*)d_in[3];
    const float* b     = (const float*)d_in[4];
    const float* gamma = (const float*)d_in[5];
    const float* beta  = (const float*)d_in[6];
    const float* Wf    = (const float*)d_in[7];
    const float* bf    = (const float*)d_in[8];
    float* out = (float*)d_out;

    const int E = in_sizes[1] / 2;
    const int N = in_sizes[2];
    const int* src = ei;
    const int* dst = ei + E;

    size_t off = 0;
    auto alloc = [&](size_t bytes) {
        void* p = (char*)d_ws + off;
        off += (bytes + 255) & ~(size_t)255;
        return p;
    };
    int*   degcnt    = (int*)alloc((size_t)N * 4);   // zeroed (only memset)
    size_t zbytes = off;
    int*   rowptr    = (int*)alloc(((size_t)N + 1) * 4);
    int*   fillcur   = (int*)alloc((size_t)N * 4);
    unsigned* esw    = (unsigned*)alloc((size_t)E * 4);
    unsigned short* wtg  = (unsigned short*)alloc((size_t)DD * DD * 2);
    unsigned short* xb   = (unsigned short*)alloc((size_t)N * DD * 2);
    unsigned short* xwb  = (unsigned short*)alloc((size_t)N * DD * 2);
    unsigned short* aggb = (unsigned short*)alloc((size_t)N * DD * 2);
    float* ps        = (float*)alloc((size_t)AGG_BLOCKS * DD * 4);
    float* ps2       = (float*)alloc((size_t)AGG_BLOCKS * DD * 4);
    float* pools     = (float*)alloc((size_t)NGRAPH * POOL_PARTS * DD * 4);
    float* colsum    = (float*)alloc(DD * 4);
    float* colsumsq  = (float*)alloc(DD * 4);
    int*   bsum      = (int*)alloc(((size_t)N / SCAN_B + 2) * 4);

    hipMemsetAsync(degcnt, 0, zbytes, stream);

    // fused degree count + x->bf16 conversion
    int nDeg = (E + 255) / 256;
    int nconv8 = (N * DD) / 8;
    int nConv = (nconv8 + 255) / 256;
    k_degxconv<<<nDeg + nConv, 256, 0, stream>>>(dst, E, degcnt, x, xb, nDeg, nconv8);

    int nblk = (N + SCAN_B - 1) / SCAN_B;
    k_scan1wt<<<nblk + DD, SCAN_B, 0, stream>>>(degcnt, N, nblk, rowptr, bsum, W, wtg);
    k_scan2<<<1, SCAN_B, 0, stream>>>(bsum, nblk, &rowptr[N]);
    k_scan3f<<<nblk, SCAN_B, 0, stream>>>(rowptr, N, bsum, fillcur);

    // fused GEMM (bf16 A) + CSR fill
    int nGemm = ((N + GBM - 1) / GBM) * 2;
    int nFill = (E + 511) / 512;
    k_gemmfill<<<nGemm + nFill, 512, 0, stream>>>(xb, wtg, xwb, N, nGemm,
                                                  src, dst, degcnt, fillcur, E, esw);

    k_aggpull<<<AGG_BLOCKS, 256, 0, stream>>>(xwb, rowptr, esw, degcnt, b, aggb, ps, ps2, N);

    k_bnred<<<DD / 4, 256, 0, stream>>>(ps, ps2, colsum, colsumsq);
    k_pool<<<NGRAPH * POOL_PARTS, 256, 0, stream>>>(aggb, batch, colsum, colsumsq, gamma, beta,
                                                    pools, N);
    k_head<<<NGRAPH, 64, 0, stream>>>(pools, batch, N, Wf, bf, out);
}

// Round 14
// 193.236 us; speedup vs baseline: 1.8953x; 1.1408x over previous
//
#include <hip/hip_runtime.h>

#define DD 256
#define NGRAPH 64
#define NCLS 60
#define BN_EPS 1e-5f
#define SCAN_B 256
#define AGG_BLOCKS 2048
#define AGG_WAVES (AGG_BLOCKS * 4)
#define POOL_PARTS 32

typedef __attribute__((ext_vector_type(8))) short bf16x8;
typedef __attribute__((ext_vector_type(4))) float f32x4;

__device__ __forceinline__ unsigned short f2bf(float f) {
    union { float f; unsigned u; } v;
    v.f = f;
    unsigned r = v.u + 0x7FFFu + ((v.u >> 16) & 1u);  // RNE
    return (unsigned short)(r >> 16);
}
__device__ __forceinline__ float bf2f(unsigned short u) {
    union { unsigned u; float f; } v;
    v.u = ((unsigned)u) << 16;
    return v.f;
}

// ---------------- fused: degree count (+rank capture) + x->bf16 convert ----------------
__global__ void k_degxconv(const int* __restrict__ dst, int E, int* __restrict__ degcnt,
                           unsigned short* __restrict__ rank,
                           const float* __restrict__ x, unsigned short* __restrict__ xb,
                           int nDeg, int nconv8) {
    if (blockIdx.x < nDeg) {
        int e = blockIdx.x * blockDim.x + threadIdx.x;
        if (e < E) {
            int pos = atomicAdd(&degcnt[dst[e]], 1);
            rank[e] = (unsigned short)pos;  // max in-degree < 65536
        }
        return;
    }
    int i = (blockIdx.x - nDeg) * blockDim.x + threadIdx.x;  // 8 floats each
    if (i >= nconv8) return;
    const float4* p = (const float4*)&x[(size_t)i * 8];
    float4 a = p[0], c = p[1];
    bf16x8 o;
    o[0] = (short)f2bf(a.x); o[1] = (short)f2bf(a.y);
    o[2] = (short)f2bf(a.z); o[3] = (short)f2bf(a.w);
    o[4] = (short)f2bf(c.x); o[5] = (short)f2bf(c.y);
    o[6] = (short)f2bf(c.z); o[7] = (short)f2bf(c.w);
    *(bf16x8*)&xb[(size_t)i * 8] = o;
}

// ---------------- scan phase 1 (blocks 0..nblk-1) + W transpose (blocks nblk..nblk+255) ----------------
__global__ __launch_bounds__(256) void k_scan1wt(const int* __restrict__ in, int n, int nblk,
                                                 int* __restrict__ out, int* __restrict__ bsum,
                                                 const float* __restrict__ W,
                                                 unsigned short* __restrict__ Wt) {
    if (blockIdx.x >= nblk) {
        int col = blockIdx.x - nblk;          // 0..255: column of W -> row of Wt
        int k = threadIdx.x;
        Wt[col * DD + k] = f2bf(W[k * DD + col]);
        return;
    }
    __shared__ int sm[SCAN_B];
    int i = blockIdx.x * SCAN_B + threadIdx.x;
    int v = (i < n) ? in[i] : 0;
    sm[threadIdx.x] = v;
    __syncthreads();
    int acc = v;
    for (int off = 1; off < SCAN_B; off <<= 1) {
        int t = (threadIdx.x >= off) ? sm[threadIdx.x - off] : 0;
        __syncthreads();
        acc += t;
        sm[threadIdx.x] = acc;
        __syncthreads();
    }
    if (i < n) out[i] = acc - v;
    if (threadIdx.x == SCAN_B - 1) bsum[blockIdx.x] = acc;
}

__global__ void k_scan2(int* __restrict__ bsum, int nb, int* __restrict__ total) {
    __shared__ int sm[SCAN_B];
    __shared__ int carry;
    if (threadIdx.x == 0) carry = 0;
    __syncthreads();
    for (int base = 0; base < nb; base += SCAN_B) {
        int i = base + threadIdx.x;
        int v = (i < nb) ? bsum[i] : 0;
        sm[threadIdx.x] = v;
        __syncthreads();
        int acc = v;
        for (int off = 1; off < SCAN_B; off <<= 1) {
            int t = (threadIdx.x >= off) ? sm[threadIdx.x - off] : 0;
            __syncthreads();
            acc += t;
            sm[threadIdx.x] = acc;
            __syncthreads();
        }
        if (i < nb) bsum[i] = carry + acc - v;
        __syncthreads();
        if (threadIdx.x == SCAN_B - 1) carry += acc;
        __syncthreads();
    }
    if (threadIdx.x == 0 && total) *total = carry;
}

// scan phase 3: finalize rowptr
__global__ void k_scan3f(int* __restrict__ rowptr, int n, const int* __restrict__ bsum) {
    int i = blockIdx.x * SCAN_B + threadIdx.x;
    if (i < n) rowptr[i] += bsum[blockIdx.x];
}

// ---------------- fused: MFMA GEMM (bf16 A, double-buffered At) + CSR fill (rank-based) ----------------
#define GBM 128
#define GBN 128
__global__ __launch_bounds__(512) void k_gemmfill(const unsigned short* __restrict__ xb,
                                                  const unsigned short* __restrict__ Wtg,
                                                  unsigned short* __restrict__ C, int M,
                                                  int nGemm,
                                                  const int* __restrict__ src,
                                                  const int* __restrict__ dst,
                                                  const unsigned short* __restrict__ rank,
                                                  const int* __restrict__ degcnt,
                                                  const int* __restrict__ rowptr, int E,
                                                  unsigned* __restrict__ esw) {
    __shared__ short Wt[GBN * 256];   // 64 KB
    __shared__ short At[2][GBM * 32]; // 2 x 8 KB
    if (blockIdx.x >= nGemm) {
        int e = (blockIdx.x - nGemm) * 512 + threadIdx.x;
        if (e >= E) return;
        int s = src[e], d = dst[e];
        float w = rsqrtf((float)(degcnt[s] + 1)) * rsqrtf((float)(degcnt[d] + 1));
        int slot = rowptr[d] + (int)rank[e];   // no atomics
        esw[slot] = (unsigned)s | ((unsigned)f2bf(w) << 16);  // N < 65536
        return;
    }

    const int tid = threadIdx.x;
    const int wave = tid >> 6;
    const int lane = tid & 63;
    const int row0 = (blockIdx.x >> 1) * GBM;
    const int n0 = (blockIdx.x & 1) * GBN;

    // stage Wt slice: 4096 chunks of 16B, 8 per thread
#pragma unroll
    for (int i = 0; i < 8; ++i) {
        int cid = tid + i * 512;
        int n = cid >> 5;
        int k0 = (cid & 31) * 8;
        bf16x8 pk = *(const bf16x8*)&Wtg[(size_t)(n0 + n) * DD + k0];
        int byte = (n * 512 + k0 * 2) ^ ((n & 7) << 4);
        *(bf16x8*)((char*)Wt + byte) = pk;
    }

    f32x4 acc[8];
#pragma unroll
    for (int j = 0; j < 8; ++j) acc[j] = (f32x4){0.f, 0.f, 0.f, 0.f};

    const int arow = tid >> 2;        // 0..127
    const int aslot = tid & 3;        // 0..3 (8 k's each)
    const int grow = row0 + arow;
    const int frow = wave * 16 + (lane & 15);   // 0..127
    const int g = lane >> 4;
    const int abyte_st = (arow * 64 + aslot * 16) ^ ((arow & 3) << 4);
    const int abyte_ld = (frow * 64 + g * 16) ^ ((frow & 3) << 4);
    const unsigned short* ap = (grow < M) ? &xb[(size_t)grow * DD + aslot * 8] : nullptr;

    bf16x8 av = (bf16x8){0, 0, 0, 0, 0, 0, 0, 0};
    if (ap) av = *(const bf16x8*)ap;

    // prologue: fill buffer 0 with kb=0 tile, prefetch kb=32
    *(bf16x8*)((char*)At[0] + abyte_st) = av;
    if (ap) av = *(const bf16x8*)(ap + 32);
    __syncthreads();

    int cur = 0;
    for (int kb = 0; kb < DD; kb += 32) {
        if (kb + 32 < DD) {
            *(bf16x8*)((char*)At[cur ^ 1] + abyte_st) = av;  // write next buffer
            if (kb + 64 < DD && ap) av = *(const bf16x8*)(ap + kb + 64);
        }
        bf16x8 af = *(const bf16x8*)((const char*)At[cur] + abyte_ld);
#pragma unroll
        for (int j = 0; j < 8; ++j) {
            int n = j * 16 + (lane & 15);
            int bbyte = (n * 512 + (kb + g * 8) * 2) ^ ((n & 7) << 4);
            bf16x8 bfr = *(const bf16x8*)((const char*)Wt + bbyte);
            acc[j] = __builtin_amdgcn_mfma_f32_16x16x32_bf16(af, bfr, acc[j], 0, 0, 0);
        }
        __syncthreads();  // next buffer written by all; cur reads done
        cur ^= 1;
    }

#pragma unroll
    for (int j = 0; j < 8; ++j) {
        int col = n0 + j * 16 + (lane & 15);
#pragma unroll
        for (int r = 0; r < 4; ++r) {
            int row = row0 + wave * 16 + g * 4 + r;
            if (row < M) C[(size_t)row * DD + col] = f2bf(acc[j][r]);
        }
    }
}

// ---------------- pull aggregation (persistent, full row/wave) + BN partials ----------------
__global__ __launch_bounds__(256) void k_aggpull(const unsigned short* __restrict__ xwb,
                                                 const int* __restrict__ rowptr,
                                                 const unsigned* __restrict__ esw,
                                                 const int* __restrict__ degcnt,
                                                 const float* __restrict__ b,
                                                 unsigned short* __restrict__ aggb,
                                                 float* __restrict__ ps,
                                                 float* __restrict__ ps2, int N) {
    __shared__ float sred[4 * DD];
    __shared__ float qred[4 * DD];
    const int lane = threadIdx.x & 63;
    const int wave = threadIdx.x >> 6;
    const int c = lane * 4;
    const int gw = (blockIdx.x * blockDim.x + threadIdx.x) >> 6;
    const float4 bb = *(const float4*)&b[c];

    float s0 = 0.f, s1 = 0.f, s2 = 0.f, s3 = 0.f;
    float q0 = 0.f, q1 = 0.f, q2 = 0.f, q3 = 0.f;

    for (int n = gw; n < N; n += AGG_WAVES) {
        float di = rsqrtf((float)(degcnt[n] + 1));
        float w0 = di * di;
        ushort4 v = *(const ushort4*)&xwb[(size_t)n * DD + c];
        float4 acc = make_float4(bf2f(v.x) * w0, bf2f(v.y) * w0, bf2f(v.z) * w0, bf2f(v.w) * w0);

        int j0 = rowptr[n], j1 = rowptr[n + 1];
        int j = j0;
        for (; j + 3 < j1; j += 4) {
            unsigned e0 = esw[j + 0], e1 = esw[j + 1], e2 = esw[j + 2], e3 = esw[j + 3];
            ushort4 u0 = *(const ushort4*)&xwb[(size_t)(e0 & 0xFFFFu) * DD + c];
            ushort4 u1 = *(const ushort4*)&xwb[(size_t)(e1 & 0xFFFFu) * DD + c];
            ushort4 u2 = *(const ushort4*)&xwb[(size_t)(e2 & 0xFFFFu) * DD + c];
            ushort4 u3 = *(const ushort4*)&xwb[(size_t)(e3 & 0xFFFFu) * DD + c];
            float wa = bf2f((unsigned short)(e0 >> 16));
            float wb = bf2f((unsigned short)(e1 >> 16));
            float wc = bf2f((unsigned short)(e2 >> 16));
            float wd = bf2f((unsigned short)(e3 >> 16));
            acc.x += bf2f(u0.x) * wa + bf2f(u1.x) * wb + bf2f(u2.x) * wc + bf2f(u3.x) * wd;
            acc.y += bf2f(u0.y) * wa + bf2f(u1.y) * wb + bf2f(u2.y) * wc + bf2f(u3.y) * wd;
            acc.z += bf2f(u0.z) * wa + bf2f(u1.z) * wb + bf2f(u2.z) * wc + bf2f(u3.z) * wd;
            acc.w += bf2f(u0.w) * wa + bf2f(u1.w) * wb + bf2f(u2.w) * wc + bf2f(u3.w) * wd;
        }
        for (; j < j1; ++j) {
            unsigned e0 = esw[j];
            float wa = bf2f((unsigned short)(e0 >> 16));
            ushort4 u0 = *(const ushort4*)&xwb[(size_t)(e0 & 0xFFFFu) * DD + c];
            acc.x += bf2f(u0.x) * wa;
            acc.y += bf2f(u0.y) * wa;
            acc.z += bf2f(u0.z) * wa;
            acc.w += bf2f(u0.w) * wa;
        }
        acc.x += bb.x;
        acc.y += bb.y;
        acc.z += bb.z;
        acc.w += bb.w;

        ushort4 o;
        o.x = f2bf(acc.x); o.y = f2bf(acc.y); o.z = f2bf(acc.z); o.w = f2bf(acc.w);
        *(ushort4*)&aggb[(size_t)n * DD + c] = o;

        s0 += acc.x; q0 += acc.x * acc.x;
        s1 += acc.y; q1 += acc.y * acc.y;
        s2 += acc.z; q2 += acc.z * acc.z;
        s3 += acc.w; q3 += acc.w * acc.w;
    }

    f32x4 sv = {s0, s1, s2, s3};
    f32x4 qv = {q0, q1, q2, q3};
    *(f32x4*)&sred[wave * DD + c] = sv;
    *(f32x4*)&qred[wave * DD + c] = qv;
    __syncthreads();
    int d = threadIdx.x;
    float s = sred[d] + sred[DD + d] + sred[2 * DD + d] + sred[3 * DD + d];
    float q = qred[d] + qred[DD + d] + qred[2 * DD + d] + qred[3 * DD + d];
    ps[(size_t)blockIdx.x * DD + d] = s;
    ps2[(size_t)blockIdx.x * DD + d] = q;
}

// ---------------- per-block partials -> colsum/colsumsq (no atomics) ----------------
__global__ __launch_bounds__(256) void k_bnred(const float* __restrict__ ps,
                                               const float* __restrict__ ps2,
                                               float* __restrict__ colsum,
                                               float* __restrict__ colsumsq) {
    __shared__ float ss[256], qq[256];
    int cgrp = threadIdx.x & 3;
    int r = threadIdx.x >> 2;  // 0..63
    int col = blockIdx.x * 4 + cgrp;
    float s = 0.f, q = 0.f;
    for (int row = r; row < AGG_BLOCKS; row += 64) {
        s += ps[(size_t)row * DD + col];
        q += ps2[(size_t)row * DD + col];
    }
    ss[threadIdx.x] = s;
    qq[threadIdx.x] = q;
    __syncthreads();
    if (threadIdx.x < 4) {
        float S = 0.f, Q = 0.f;
        for (int k = threadIdx.x; k < 256; k += 4) { S += ss[k]; Q += qq[k]; }
        colsum[blockIdx.x * 4 + threadIdx.x] = S;
        colsumsq[blockIdx.x * 4 + threadIdx.x] = Q;
    }
}

// ---------------- BN-apply + ReLU + per-graph-slice pooled partials (no atomics) ----------------
__global__ __launch_bounds__(256) void k_pool(const unsigned short* __restrict__ aggb,
                                              const int* __restrict__ batch,
                                              const float* __restrict__ colsum,
                                              const float* __restrict__ colsumsq,
                                              const float* __restrict__ gamma,
                                              const float* __restrict__ beta,
                                              float* __restrict__ pools, int N) {
    int g = blockIdx.x / POOL_PARTS;
    int p = blockIdx.x % POOL_PARTS;
    int d = threadIdx.x;
    int lo = 0, hi = N;
    while (lo < hi) { int mid = (lo + hi) >> 1; if (batch[mid] < g) lo = mid + 1; else hi = mid; }
    int start = lo;
    lo = 0; hi = N;
    while (lo < hi) { int mid = (lo + hi) >> 1; if (batch[mid] < g + 1) lo = mid + 1; else hi = mid; }
    int len = lo - start;
    int s0 = start + (len * p) / POOL_PARTS;
    int s1 = start + (len * (p + 1)) / POOL_PARTS;

    float m = colsum[d] / (float)N;
    float var = colsumsq[d] / (float)N - m * m;
    float rs = rsqrtf(var + BN_EPS);
    float gm = gamma[d], bt = beta[d];
    float acc = 0.f;
    for (int n = s0; n < s1; ++n) {
        float a = bf2f(aggb[(size_t)n * DD + d]);
        acc += fmaxf(gm * (a - m) * rs + bt, 0.f);
    }
    pools[(size_t)blockIdx.x * DD + d] = acc;
}

// ---------------- head: count + partial-reduce + mean + FC + log_softmax ----------------
__global__ void k_head(const float* __restrict__ pools, const int* __restrict__ batch, int N,
                       const float* __restrict__ Wf, const float* __restrict__ bfv,
                       float* __restrict__ out) {
    int g = blockIdx.x;
    int lane = threadIdx.x;
    __shared__ float pm[DD];
    int lo = 0, hi = N;
    while (lo < hi) { int mid = (lo + hi) >> 1; if (batch[mid] < g) lo = mid + 1; else hi = mid; }
    int start = lo;
    lo = 0; hi = N;
    while (lo < hi) { int mid = (lo + hi) >> 1; if (batch[mid] < g + 1) lo = mid + 1; else hi = mid; }
    float cinv = 1.0f / fmaxf((float)(lo - start), 1.0f);

    for (int k = lane; k < DD; k += 64) {
        float s = 0.f;
#pragma unroll
        for (int p = 0; p < POOL_PARTS; ++p)
            s += pools[((size_t)g * POOL_PARTS + p) * DD + k];
        pm[k] = s * cinv;
    }
    __syncthreads();
    float logit = -INFINITY;
    if (lane < NCLS) {
        float s = bfv[lane];
        for (int k = 0; k < DD; ++k) s += pm[k] * Wf[lane * DD + k];
        logit = s;
    }
    float mx = logit;
#pragma unroll
    for (int off = 32; off; off >>= 1) mx = fmaxf(mx, __shfl_xor(mx, off));
    float ex = (lane < NCLS) ? expf(logit - mx) : 0.f;
    float sum = ex;
#pragma unroll
    for (int off = 32; off; off >>= 1) sum += __shfl_xor(sum, off);
    if (lane < NCLS) out[g * NCLS + lane] = logit - mx - logf(sum);
}

extern "C" void kernel_launch(void* const* d_in, const int* in_sizes, int n_in,
                              void* d_out, int out_size, void* d_ws, size_t ws_size,
                              hipStream_t stream) {
    const float* x     = (const float*)d_in[0];
    const int*   ei    = (const int*)d_in[1];
    const int*   batch = (const int*)d_in[2];
    const float* W     = (const float*)d_in[3];
    const float* b     = (const float*)d_in[4];
    const float* gamma = (const float*)d_in[5];
    const float* beta  = (const float*)d_in[6];
    const float* Wf    = (const float*)d_in[7];
    const float* bf    = (const float*)d_in[8];
    float* out = (float*)d_out;

    const int E = in_sizes[1] / 2;
    const int N = in_sizes[2];
    const int* src = ei;
    const int* dst = ei + E;

    size_t off = 0;
    auto alloc = [&](size_t bytes) {
        void* p = (char*)d_ws + off;
        off += (bytes + 255) & ~(size_t)255;
        return p;
    };
    int*   degcnt    = (int*)alloc((size_t)N * 4);   // zeroed (only memset)
    size_t zbytes = off;
    int*   rowptr    = (int*)alloc(((size_t)N + 1) * 4);
    unsigned short* rank = (unsigned short*)alloc((size_t)E * 2);
    unsigned* esw    = (unsigned*)alloc((size_t)E * 4);
    unsigned short* wtg  = (unsigned short*)alloc((size_t)DD * DD * 2);
    unsigned short* xb   = (unsigned short*)alloc((size_t)N * DD * 2);
    unsigned short* xwb  = (unsigned short*)alloc((size_t)N * DD * 2);
    unsigned short* aggb = (unsigned short*)alloc((size_t)N * DD * 2);
    float* ps        = (float*)alloc((size_t)AGG_BLOCKS * DD * 4);
    float* ps2       = (float*)alloc((size_t)AGG_BLOCKS * DD * 4);
    float* pools     = (float*)alloc((size_t)NGRAPH * POOL_PARTS * DD * 4);
    float* colsum    = (float*)alloc(DD * 4);
    float* colsumsq  = (float*)alloc(DD * 4);
    int*   bsum      = (int*)alloc(((size_t)N / SCAN_B + 2) * 4);

    hipMemsetAsync(degcnt, 0, zbytes, stream);

    // fused degree count (+rank) + x->bf16 conversion
    int nDeg = (E + 255) / 256;
    int nconv8 = (N * DD) / 8;
    int nConv = (nconv8 + 255) / 256;
    k_degxconv<<<nDeg + nConv, 256, 0, stream>>>(dst, E, degcnt, rank, x, xb, nDeg, nconv8);

    int nblk = (N + SCAN_B - 1) / SCAN_B;
    k_scan1wt<<<nblk + DD, SCAN_B, 0, stream>>>(degcnt, N, nblk, rowptr, bsum, W, wtg);
    k_scan2<<<1, SCAN_B, 0, stream>>>(bsum, nblk, &rowptr[N]);
    k_scan3f<<<nblk, SCAN_B, 0, stream>>>(rowptr, N, bsum);

    // fused GEMM (bf16 A, dbuf At) + CSR fill (rank-based, no atomics)
    int nGemm = ((N + GBM - 1) / GBM) * 2;
    int nFill = (E + 511) / 512;
    k_gemmfill<<<nGemm + nFill, 512, 0, stream>>>(xb, wtg, xwb, N, nGemm,
                                                  src, dst, rank, degcnt, rowptr, E, esw);

    k_aggpull<<<AGG_BLOCKS, 256, 0, stream>>>(xwb, rowptr, esw, degcnt, b, aggb, ps, ps2, N);

    k_bnred<<<DD / 4, 256, 0, stream>>>(ps, ps2, colsum, colsumsq);
    k_pool<<<NGRAPH * POOL_PARTS, 256, 0, stream>>>(aggb, batch, colsum, colsumsq, gamma, beta,
                                                    pools, N);
    k_head<<<NGRAPH, 64, 0, stream>>>(pools, batch, N, Wf, bf, out);
}

// Round 15
// 192.242 us; speedup vs baseline: 1.9051x; 1.0052x over previous
//
#include <hip/hip_runtime.h>

#define DD 256
#define NGRAPH 64
#define NCLS 60
#define BN_EPS 1e-5f
#define SCAN_B 256
#define AGG_BLOCKS 2048
#define AGG_WAVES (AGG_BLOCKS * 4)
#define POOL_PARTS 32

typedef __attribute__((ext_vector_type(8))) short bf16x8;
typedef __attribute__((ext_vector_type(4))) float f32x4;

__device__ __forceinline__ unsigned short f2bf(float f) {
    union { float f; unsigned u; } v;
    v.f = f;
    unsigned r = v.u + 0x7FFFu + ((v.u >> 16) & 1u);  // RNE
    return (unsigned short)(r >> 16);
}
__device__ __forceinline__ float bf2f(unsigned short u) {
    union { unsigned u; float f; } v;
    v.u = ((unsigned)u) << 16;
    return v.f;
}

// async 16B/lane global->LDS DMA; lds base must be wave-uniform, global addr per-lane
__device__ __forceinline__ void gload16(const void* g, void* l) {
    __builtin_amdgcn_global_load_lds(
        (const __attribute__((address_space(1))) unsigned int*)g,
        (__attribute__((address_space(3))) unsigned int*)l, 16, 0, 0);
}

// ---------------- fused: degree count (+rank capture) + x->bf16 convert ----------------
__global__ void k_degxconv(const int* __restrict__ dst, int E, int* __restrict__ degcnt,
                           unsigned short* __restrict__ rank,
                           const float* __restrict__ x, unsigned short* __restrict__ xb,
                           int nDeg, int nconv8) {
    if (blockIdx.x < nDeg) {
        int e = blockIdx.x * blockDim.x + threadIdx.x;
        if (e < E) {
            int pos = atomicAdd(&degcnt[dst[e]], 1);
            rank[e] = (unsigned short)pos;  // max in-degree < 65536
        }
        return;
    }
    int i = (blockIdx.x - nDeg) * blockDim.x + threadIdx.x;  // 8 floats each
    if (i >= nconv8) return;
    const float4* p = (const float4*)&x[(size_t)i * 8];
    float4 a = p[0], c = p[1];
    bf16x8 o;
    o[0] = (short)f2bf(a.x); o[1] = (short)f2bf(a.y);
    o[2] = (short)f2bf(a.z); o[3] = (short)f2bf(a.w);
    o[4] = (short)f2bf(c.x); o[5] = (short)f2bf(c.y);
    o[6] = (short)f2bf(c.z); o[7] = (short)f2bf(c.w);
    *(bf16x8*)&xb[(size_t)i * 8] = o;
}

// ---------------- scan phase 1 (blocks 0..nblk-1) + W transpose PRE-SWIZZLED (blocks nblk..) --------
// wtg layout: two 32768-u16 halves (cols 0-127 / 128-255 of W^T); within half h, element
// (n,k) lives at u16 index ((n*256 + k) ^ ((n&7)<<3)) == LDS image for the GEMM's swizzled reads.
__global__ __launch_bounds__(256) void k_scan1wt(const int* __restrict__ in, int n, int nblk,
                                                 int* __restrict__ out, int* __restrict__ bsum,
                                                 const float* __restrict__ W,
                                                 unsigned short* __restrict__ Wt) {
    if (blockIdx.x >= nblk) {
        int col = blockIdx.x - nblk;          // 0..255: column of W -> row of Wt
        int half = col >> 7;
        int nr = col & 127;
        int k = threadIdx.x;
        Wt[half * 32768 + (((nr * 256) + k) ^ ((nr & 7) << 3))] = f2bf(W[k * DD + col]);
        return;
    }
    __shared__ int sm[SCAN_B];
    int i = blockIdx.x * SCAN_B + threadIdx.x;
    int v = (i < n) ? in[i] : 0;
    sm[threadIdx.x] = v;
    __syncthreads();
    int acc = v;
    for (int off = 1; off < SCAN_B; off <<= 1) {
        int t = (threadIdx.x >= off) ? sm[threadIdx.x - off] : 0;
        __syncthreads();
        acc += t;
        sm[threadIdx.x] = acc;
        __syncthreads();
    }
    if (i < n) out[i] = acc - v;  // block-local exclusive prefix
    if (threadIdx.x == SCAN_B - 1) bsum[blockIdx.x] = acc;
}

__global__ void k_scan2(int* __restrict__ bsum, int nb) {
    __shared__ int sm[SCAN_B];
    __shared__ int carry;
    if (threadIdx.x == 0) carry = 0;
    __syncthreads();
    for (int base = 0; base < nb; base += SCAN_B) {
        int i = base + threadIdx.x;
        int v = (i < nb) ? bsum[i] : 0;
        sm[threadIdx.x] = v;
        __syncthreads();
        int acc = v;
        for (int off = 1; off < SCAN_B; off <<= 1) {
            int t = (threadIdx.x >= off) ? sm[threadIdx.x - off] : 0;
            __syncthreads();
            acc += t;
            sm[threadIdx.x] = acc;
            __syncthreads();
        }
        if (i < nb) bsum[i] = carry + acc - v;
        __syncthreads();
        if (threadIdx.x == SCAN_B - 1) carry += acc;
        __syncthreads();
    }
}

// ---------------- fused: MFMA GEMM (async LDS staging) + CSR fill (rank-based) ----------------
#define GBM 128
#define GBN 128
__global__ __launch_bounds__(512) void k_gemmfill(const unsigned short* __restrict__ xb,
                                                  const unsigned short* __restrict__ Wtg,
                                                  unsigned short* __restrict__ C, int M,
                                                  int nGemm,
                                                  const int* __restrict__ src,
                                                  const int* __restrict__ dst,
                                                  const unsigned short* __restrict__ rank,
                                                  const int* __restrict__ degcnt,
                                                  const int* __restrict__ rp1,
                                                  const int* __restrict__ bsum, int E,
                                                  unsigned* __restrict__ esw) {
    __shared__ short Wt[GBN * 256];   // 64 KB, swizzled image (linear copy of wtg half)
    __shared__ short At[2][GBM * 32]; // 2 x 8 KB, swizzled image
    if (blockIdx.x >= nGemm) {
        int e = (blockIdx.x - nGemm) * 512 + threadIdx.x;
        if (e >= E) return;
        int s = src[e], d = dst[e];
        float w = rsqrtf((float)(degcnt[s] + 1)) * rsqrtf((float)(degcnt[d] + 1));
        int slot = rp1[d] + bsum[d >> 8] + (int)rank[e];   // no atomics
        esw[slot] = (unsigned)s | ((unsigned)f2bf(w) << 16);  // N < 65536
        return;
    }

    const int tid = threadIdx.x;
    const int wave = tid >> 6;
    const int lane = tid & 63;
    const int row0 = (blockIdx.x >> 1) * GBM;
    const int half = blockIdx.x & 1;
    const int n0 = half * GBN;

    // per-lane inverse-swizzled At source: LDS linear pos p = wave*1024B + lane*16B holds
    // A row (p>>6), k-slot ((p>>4)&3) ^ (row&3)
    const int arowl = wave * 16 + (lane >> 2);
    const int asl = (((lane & 3) ^ ((lane >> 2) & 3))) * 8;
    const unsigned short* agsrc = &xb[(size_t)(row0 + arowl) * DD + asl];
    short* atdst0 = &At[0][wave * 512];   // u16 idx; byte = wave*1024
    short* atdst1 = &At[1][wave * 512];

    // prologue: issue At(kb=0) + full Wt slice (linear DMA of pre-swizzled wtg half)
    gload16(agsrc, atdst0);
    const unsigned short* wg = Wtg + half * 32768;
#pragma unroll
    for (int j = 0; j < 8; ++j) {
        int chunk = (wave * 8 + j) * 512;        // u16 per wave-instruction = 64 lanes * 8
        gload16(wg + chunk + lane * 8, &Wt[chunk]);
    }
    __syncthreads();  // drains vmcnt -> everything staged

    f32x4 acc[8];
#pragma unroll
    for (int j = 0; j < 8; ++j) acc[j] = (f32x4){0.f, 0.f, 0.f, 0.f};

    const int frow = wave * 16 + (lane & 15);   // 0..127
    const int g = lane >> 4;
    const int abyte_ld = (frow * 64 + g * 16) ^ ((frow & 3) << 4);

    int cur = 0;
    for (int kb = 0; kb < DD; kb += 32) {
        if (kb + 32 < DD)  // issue next-buffer DMA; drained by this iteration's barrier
            gload16(agsrc + kb + 32, cur ? atdst0 : atdst1);

        bf16x8 af = *(const bf16x8*)((const char*)At[cur] + abyte_ld);
#pragma unroll
        for (int j = 0; j < 8; ++j) {
            int n = j * 16 + (lane & 15);
            int bbyte = (n * 512 + (kb + g * 8) * 2) ^ ((n & 7) << 4);
            bf16x8 bfr = *(const bf16x8*)((const char*)Wt + bbyte);
            acc[j] = __builtin_amdgcn_mfma_f32_16x16x32_bf16(af, bfr, acc[j], 0, 0, 0);
        }
        __syncthreads();
        cur ^= 1;
    }

#pragma unroll
    for (int j = 0; j < 8; ++j) {
        int col = n0 + j * 16 + (lane & 15);
#pragma unroll
        for (int r = 0; r < 4; ++r) {
            int row = row0 + wave * 16 + g * 4 + r;
            if (row < M) C[(size_t)row * DD + col] = f2bf(acc[j][r]);
        }
    }
}

// ---------------- pull aggregation (persistent, full row/wave) + BN partials ----------------
__global__ __launch_bounds__(256) void k_aggpull(const unsigned short* __restrict__ xwb,
                                                 const int* __restrict__ rp1,
                                                 const int* __restrict__ bsum,
                                                 const unsigned* __restrict__ esw,
                                                 const int* __restrict__ degcnt,
                                                 const float* __restrict__ b,
                                                 unsigned short* __restrict__ aggb,
                                                 float* __restrict__ ps,
                                                 float* __restrict__ ps2, int N) {
    __shared__ float sred[4 * DD];
    __shared__ float qred[4 * DD];
    const int lane = threadIdx.x & 63;
    const int wave = threadIdx.x >> 6;
    const int c = lane * 4;
    const int gw = (blockIdx.x * blockDim.x + threadIdx.x) >> 6;
    const float4 bb = *(const float4*)&b[c];

    float s0 = 0.f, s1 = 0.f, s2 = 0.f, s3 = 0.f;
    float q0 = 0.f, q1 = 0.f, q2 = 0.f, q3 = 0.f;

    for (int n = gw; n < N; n += AGG_WAVES) {
        int deg = degcnt[n];
        float di = rsqrtf((float)(deg + 1));
        float w0 = di * di;
        ushort4 v = *(const ushort4*)&xwb[(size_t)n * DD + c];
        float4 acc = make_float4(bf2f(v.x) * w0, bf2f(v.y) * w0, bf2f(v.z) * w0, bf2f(v.w) * w0);

        int j0 = rp1[n] + bsum[n >> 8];
        int j1 = j0 + deg;
        int j = j0;
        for (; j + 3 < j1; j += 4) {
            unsigned e0 = esw[j + 0], e1 = esw[j + 1], e2 = esw[j + 2], e3 = esw[j + 3];
            ushort4 u0 = *(const ushort4*)&xwb[(size_t)(e0 & 0xFFFFu) * DD + c];
            ushort4 u1 = *(const ushort4*)&xwb[(size_t)(e1 & 0xFFFFu) * DD + c];
            ushort4 u2 = *(const ushort4*)&xwb[(size_t)(e2 & 0xFFFFu) * DD + c];
            ushort4 u3 = *(const ushort4*)&xwb[(size_t)(e3 & 0xFFFFu) * DD + c];
            float wa = bf2f((unsigned short)(e0 >> 16));
            float wb = bf2f((unsigned short)(e1 >> 16));
            float wc = bf2f((unsigned short)(e2 >> 16));
            float wd = bf2f((unsigned short)(e3 >> 16));
            acc.x += bf2f(u0.x) * wa + bf2f(u1.x) * wb + bf2f(u2.x) * wc + bf2f(u3.x) * wd;
            acc.y += bf2f(u0.y) * wa + bf2f(u1.y) * wb + bf2f(u2.y) * wc + bf2f(u3.y) * wd;
            acc.z += bf2f(u0.z) * wa + bf2f(u1.z) * wb + bf2f(u2.z) * wc + bf2f(u3.z) * wd;
            acc.w += bf2f(u0.w) * wa + bf2f(u1.w) * wb + bf2f(u2.w) * wc + bf2f(u3.w) * wd;
        }
        for (; j < j1; ++j) {
            unsigned e0 = esw[j];
            float wa = bf2f((unsigned short)(e0 >> 16));
            ushort4 u0 = *(const ushort4*)&xwb[(size_t)(e0 & 0xFFFFu) * DD + c];
            acc.x += bf2f(u0.x) * wa;
            acc.y += bf2f(u0.y) * wa;
            acc.z += bf2f(u0.z) * wa;
            acc.w += bf2f(u0.w) * wa;
        }
        acc.x += bb.x;
        acc.y += bb.y;
        acc.z += bb.z;
        acc.w += bb.w;

        ushort4 o;
        o.x = f2bf(acc.x); o.y = f2bf(acc.y); o.z = f2bf(acc.z); o.w = f2bf(acc.w);
        *(ushort4*)&aggb[(size_t)n * DD + c] = o;

        s0 += acc.x; q0 += acc.x * acc.x;
        s1 += acc.y; q1 += acc.y * acc.y;
        s2 += acc.z; q2 += acc.z * acc.z;
        s3 += acc.w; q3 += acc.w * acc.w;
    }

    f32x4 sv = {s0, s1, s2, s3};
    f32x4 qv = {q0, q1, q2, q3};
    *(f32x4*)&sred[wave * DD + c] = sv;
    *(f32x4*)&qred[wave * DD + c] = qv;
    __syncthreads();
    int d = threadIdx.x;
    float s = sred[d] + sred[DD + d] + sred[2 * DD + d] + sred[3 * DD + d];
    float q = qred[d] + qred[DD + d] + qred[2 * DD + d] + qred[3 * DD + d];
    ps[(size_t)blockIdx.x * DD + d] = s;
    ps2[(size_t)blockIdx.x * DD + d] = q;
}

// ---------------- per-block partials -> colsum/colsumsq (no atomics) ----------------
__global__ __launch_bounds__(256) void k_bnred(const float* __restrict__ ps,
                                               const float* __restrict__ ps2,
                                               float* __restrict__ colsum,
                                               float* __restrict__ colsumsq) {
    __shared__ float ss[256], qq[256];
    int cgrp = threadIdx.x & 3;
    int r = threadIdx.x >> 2;  // 0..63
    int col = blockIdx.x * 4 + cgrp;
    float s = 0.f, q = 0.f;
    for (int row = r; row < AGG_BLOCKS; row += 64) {
        s += ps[(size_t)row * DD + col];
        q += ps2[(size_t)row * DD + col];
    }
    ss[threadIdx.x] = s;
    qq[threadIdx.x] = q;
    __syncthreads();
    if (threadIdx.x < 4) {
        float S = 0.f, Q = 0.f;
        for (int k = threadIdx.x; k < 256; k += 4) { S += ss[k]; Q += qq[k]; }
        colsum[blockIdx.x * 4 + threadIdx.x] = S;
        colsumsq[blockIdx.x * 4 + threadIdx.x] = Q;
    }
}

// ---------------- BN-apply + ReLU + per-graph-slice pooled partials (no atomics) ----------------
__global__ __launch_bounds__(256) void k_pool(const unsigned short* __restrict__ aggb,
                                              const int* __restrict__ batch,
                                              const float* __restrict__ colsum,
                                              const float* __restrict__ colsumsq,
                                              const float* __restrict__ gamma,
                                              const float* __restrict__ beta,
                                              float* __restrict__ pools, int N) {
    int g = blockIdx.x / POOL_PARTS;
    int p = blockIdx.x % POOL_PARTS;
    int d = threadIdx.x;
    int lo = 0, hi = N;
    while (lo < hi) { int mid = (lo + hi) >> 1; if (batch[mid] < g) lo = mid + 1; else hi = mid; }
    int start = lo;
    lo = 0; hi = N;
    while (lo < hi) { int mid = (lo + hi) >> 1; if (batch[mid] < g + 1) lo = mid + 1; else hi = mid; }
    int len = lo - start;
    int s0 = start + (len * p) / POOL_PARTS;
    int s1 = start + (len * (p + 1)) / POOL_PARTS;

    float m = colsum[d] / (float)N;
    float var = colsumsq[d] / (float)N - m * m;
    float rs = rsqrtf(var + BN_EPS);
    float gm = gamma[d], bt = beta[d];
    float acc = 0.f;
    for (int n = s0; n < s1; ++n) {
        float a = bf2f(aggb[(size_t)n * DD + d]);
        acc += fmaxf(gm * (a - m) * rs + bt, 0.f);
    }
    pools[(size_t)blockIdx.x * DD + d] = acc;
}

// ---------------- head: count + partial-reduce + mean + FC + log_softmax ----------------
__global__ void k_head(const float* __restrict__ pools, const int* __restrict__ batch, int N,
                       const float* __restrict__ Wf, const float* __restrict__ bfv,
                       float* __restrict__ out) {
    int g = blockIdx.x;
    int lane = threadIdx.x;
    __shared__ float pm[DD];
    int lo = 0, hi = N;
    while (lo < hi) { int mid = (lo + hi) >> 1; if (batch[mid] < g) lo = mid + 1; else hi = mid; }
    int start = lo;
    lo = 0; hi = N;
    while (lo < hi) { int mid = (lo + hi) >> 1; if (batch[mid] < g + 1) lo = mid + 1; else hi = mid; }
    float cinv = 1.0f / fmaxf((float)(lo - start), 1.0f);

    for (int k = lane; k < DD; k += 64) {
        float s = 0.f;
#pragma unroll
        for (int p = 0; p < POOL_PARTS; ++p)
            s += pools[((size_t)g * POOL_PARTS + p) * DD + k];
        pm[k] = s * cinv;
    }
    __syncthreads();
    float logit = -INFINITY;
    if (lane < NCLS) {
        float s = bfv[lane];
        for (int k = 0; k < DD; ++k) s += pm[k] * Wf[lane * DD + k];
        logit = s;
    }
    float mx = logit;
#pragma unroll
    for (int off = 32; off; off >>= 1) mx = fmaxf(mx, __shfl_xor(mx, off));
    float ex = (lane < NCLS) ? expf(logit - mx) : 0.f;
    float sum = ex;
#pragma unroll
    for (int off = 32; off; off >>= 1) sum += __shfl_xor(sum, off);
    if (lane < NCLS) out[g * NCLS + lane] = logit - mx - logf(sum);
}

extern "C" void kernel_launch(void* const* d_in, const int* in_sizes, int n_in,
                              void* d_out, int out_size, void* d_ws, size_t ws_size,
                              hipStream_t stream) {
    const float* x     = (const float*)d_in[0];
    const int*   ei    = (const int*)d_in[1];
    const int*   batch = (const int*)d_in[2];
    const float* W     = (const float*)d_in[3];
    const float* b     = (const float*)d_in[4];
    const float* gamma = (const float*)d_in[5];
    const float* beta  = (const float*)d_in[6];
    const float* Wf    = (const float*)d_in[7];
    const float* bf    = (const float*)d_in[8];
    float* out = (float*)d_out;

    const int E = in_sizes[1] / 2;
    const int N = in_sizes[2];
    const int* src = ei;
    const int* dst = ei + E;

    size_t off = 0;
    auto alloc = [&](size_t bytes) {
        void* p = (char*)d_ws + off;
        off += (bytes + 255) & ~(size_t)255;
        return p;
    };
    int*   degcnt    = (int*)alloc((size_t)N * 4);   // zeroed (only memset)
    size_t zbytes = off;
    int*   rp1       = (int*)alloc((size_t)N * 4);   // block-local exclusive prefix
    unsigned short* rank = (unsigned short*)alloc((size_t)E * 2);
    unsigned* esw    = (unsigned*)alloc((size_t)E * 4);
    unsigned short* wtg  = (unsigned short*)alloc((size_t)DD * DD * 2);  // pre-swizzled, 2 halves
    unsigned short* xb   = (unsigned short*)alloc((size_t)N * DD * 2);
    unsigned short* xwb  = (unsigned short*)alloc((size_t)N * DD * 2);
    unsigned short* aggb = (unsigned short*)alloc((size_t)N * DD * 2);
    float* ps        = (float*)alloc((size_t)AGG_BLOCKS * DD * 4);
    float* ps2       = (float*)alloc((size_t)AGG_BLOCKS * DD * 4);
    float* pools     = (float*)alloc((size_t)NGRAPH * POOL_PARTS * DD * 4);
    float* colsum    = (float*)alloc(DD * 4);
    float* colsumsq  = (float*)alloc(DD * 4);
    int*   bsum      = (int*)alloc(((size_t)N / SCAN_B + 2) * 4);

    hipMemsetAsync(degcnt, 0, zbytes, stream);

    // fused degree count (+rank) + x->bf16 conversion
    int nDeg = (E + 255) / 256;
    int nconv8 = (N * DD) / 8;
    int nConv = (nconv8 + 255) / 256;
    k_degxconv<<<nDeg + nConv, 256, 0, stream>>>(dst, E, degcnt, rank, x, xb, nDeg, nconv8);

    int nblk = (N + SCAN_B - 1) / SCAN_B;
    k_scan1wt<<<nblk + DD, SCAN_B, 0, stream>>>(degcnt, N, nblk, rp1, bsum, W, wtg);
    k_scan2<<<1, SCAN_B, 0, stream>>>(bsum, nblk);

    // fused GEMM (async-staged bf16) + CSR fill (rank-based, no atomics)
    int nGemm = ((N + GBM - 1) / GBM) * 2;
    int nFill = (E + 511) / 512;
    k_gemmfill<<<nGemm + nFill, 512, 0, stream>>>(xb, wtg, xwb, N, nGemm,
                                                  src, dst, rank, degcnt, rp1, bsum, E, esw);

    k_aggpull<<<AGG_BLOCKS, 256, 0, stream>>>(xwb, rp1, bsum, esw, degcnt, b, aggb, ps, ps2, N);

    k_bnred<<<DD / 4, 256, 0, stream>>>(ps, ps2, colsum, colsumsq);
    k_pool<<<NGRAPH * POOL_PARTS, 256, 0, stream>>>(aggb, batch, colsum, colsumsq, gamma, beta,
                                                    pools, N);
    k_head<<<NGRAPH, 64, 0, stream>>>(pools, batch, N, Wf, bf, out);
}